// Round 5
// baseline (1530.587 us; speedup 1.0000x reference)
//
#include <hip/hip_runtime.h>

#define NG 64    // graphs
#define NB 384   // poolgemm partial blocks

__device__ __forceinline__ ushort f2bf(float f) {
    unsigned int b = __float_as_uint(f);
    b += 0x7fffu + ((b >> 16) & 1u);   // RTNE
    return (ushort)(b >> 16);
}

// ---------------- histogram (int atomics) — edge-dst only ----------------
__global__ void hist_kernel(const int* __restrict__ idx, int n, int* __restrict__ cnt) {
    int i = blockIdx.x * blockDim.x + threadIdx.x;
    int stride = gridDim.x * blockDim.x;
    for (; i < n; i += stride) atomicAdd(&cnt[idx[i]], 1);
}

// ---------------- 3-way exclusive scan -> row_ptr (shfl-based) ----------------
__global__ __launch_bounds__(1024) void scan3_kernel(
    const int* __restrict__ c0, int* __restrict__ r0, int n0,
    const int* __restrict__ c1, int* __restrict__ r1, int n1,
    const int* __restrict__ c2, int* __restrict__ r2, int n2)
{
    const int* c = blockIdx.x == 0 ? c0 : (blockIdx.x == 1 ? c1 : c2);
    int*       r = blockIdx.x == 0 ? r0 : (blockIdx.x == 1 ? r1 : r2);
    int        N = blockIdx.x == 0 ? n0 : (blockIdx.x == 1 ? n1 : n2);
    __shared__ int wsum[16];
    __shared__ int carry;
    int t = threadIdx.x, lane = t & 63, wv = t >> 6;
    if (t == 0) { carry = 0; r[0] = 0; }
    __syncthreads();
    for (int base = 0; base < N; base += 1024) {
        int i = base + t;
        int x = (i < N) ? c[i] : 0;
        #pragma unroll
        for (int off = 1; off < 64; off <<= 1) {
            int u = __shfl_up(x, off, 64);
            if (lane >= off) x += u;
        }
        if (lane == 63) wsum[wv] = x;
        __syncthreads();
        if (wv == 0 && lane < 16) {
            int v = wsum[lane];
            #pragma unroll
            for (int off = 1; off < 16; off <<= 1) {
                int u = __shfl_up(v, off, 64);
                if (lane >= off) v += u;
            }
            wsum[lane] = v;
        }
        __syncthreads();
        int add = carry + (wv > 0 ? wsum[wv - 1] : 0);
        if (i < N) r[i + 1] = x + add;
        int tot = wsum[15];
        __syncthreads();
        if (t == 0) carry += tot;
        __syncthreads();
    }
}

// ---------------- CSR fill ----------------
__global__ void fill_kernel(const int* __restrict__ src, const int* __restrict__ dst, int E,
                            const int* __restrict__ rp, int* __restrict__ cur, int* __restrict__ csr)
{
    int i = blockIdx.x * blockDim.x + threadIdx.x;
    int stride = gridDim.x * blockDim.x;
    for (; i < E; i += stride) {
        int d = dst[i];
        int pos = rp[d] + atomicAdd(&cur[d], 1);
        csr[pos] = src[i];
    }
}

// ---------------- elementwise add (weight/bias sums) ----------------
__global__ void add2_kernel(const float* __restrict__ a, const float* __restrict__ b,
                            float* __restrict__ o, int n) {
    int i = blockIdx.x * blockDim.x + threadIdx.x;
    if (i < n) o[i] = a[i] + b[i];
}

// ---------------- f32 -> bf16 conversion (4 elems/thread) ----------------
__global__ void cvt_kernel(const float* __restrict__ x, ushort* __restrict__ o, int n4) {
    int i = blockIdx.x * blockDim.x + threadIdx.x;
    if (i >= n4) return;
    float4 v = ((const float4*)x)[i];
    ushort4 r;
    r.x = f2bf(v.x); r.y = f2bf(v.y); r.z = f2bf(v.z); r.w = f2bf(v.w);
    ((ushort4*)o)[i] = r;
}

// ---------------- graph boundaries via binary search (batch is sorted) ----------------
__global__ void bounds_kernel(const int* __restrict__ bu, int nu,
                              const int* __restrict__ bd, int nd,
                              int* __restrict__ bndu, int* __restrict__ bndd)
{
    const int* b = blockIdx.x == 0 ? bu : bd;
    int        n = blockIdx.x == 0 ? nu : nd;
    int*       o = blockIdx.x == 0 ? bndu : bndd;
    int g = threadIdx.x;
    if (g > NG) return;
    int lo = 0, hi = n;
    while (lo < hi) { int m = (lo + hi) >> 1; if (b[m] < g) lo = m + 1; else hi = m; }
    o[g] = lo;
}

// ---------------- CSR mean aggregation: bf16 gather -> bf16 mean rows ----------------
__global__ __launch_bounds__(256) void agg_kernel(
    const ushort* __restrict__ xb,
    const int* __restrict__ rp, const int* __restrict__ csr, int M,
    ushort* __restrict__ mean)
{
    int wave = threadIdx.x >> 6, lane = threadIdx.x & 63;
    int row = blockIdx.x * 4 + wave;
    if (row >= M) return;
    int s0 = rp[row], s1 = rp[row + 1];
    float ax = 0.f, ay = 0.f;
    int j = s0;
    for (; j + 8 <= s1; j += 8) {
        unsigned int v0 = *(const unsigned int*)&xb[(size_t)csr[j + 0] * 128 + lane * 2];
        unsigned int v1 = *(const unsigned int*)&xb[(size_t)csr[j + 1] * 128 + lane * 2];
        unsigned int v2 = *(const unsigned int*)&xb[(size_t)csr[j + 2] * 128 + lane * 2];
        unsigned int v3 = *(const unsigned int*)&xb[(size_t)csr[j + 3] * 128 + lane * 2];
        unsigned int v4 = *(const unsigned int*)&xb[(size_t)csr[j + 4] * 128 + lane * 2];
        unsigned int v5 = *(const unsigned int*)&xb[(size_t)csr[j + 5] * 128 + lane * 2];
        unsigned int v6 = *(const unsigned int*)&xb[(size_t)csr[j + 6] * 128 + lane * 2];
        unsigned int v7 = *(const unsigned int*)&xb[(size_t)csr[j + 7] * 128 + lane * 2];
        ax += __uint_as_float(v0 << 16) + __uint_as_float(v1 << 16)
            + __uint_as_float(v2 << 16) + __uint_as_float(v3 << 16)
            + __uint_as_float(v4 << 16) + __uint_as_float(v5 << 16)
            + __uint_as_float(v6 << 16) + __uint_as_float(v7 << 16);
        ay += __uint_as_float(v0 & 0xffff0000u) + __uint_as_float(v1 & 0xffff0000u)
            + __uint_as_float(v2 & 0xffff0000u) + __uint_as_float(v3 & 0xffff0000u)
            + __uint_as_float(v4 & 0xffff0000u) + __uint_as_float(v5 & 0xffff0000u)
            + __uint_as_float(v6 & 0xffff0000u) + __uint_as_float(v7 & 0xffff0000u);
    }
    for (; j < s1; ++j) {
        unsigned int v = *(const unsigned int*)&xb[(size_t)csr[j] * 128 + lane * 2];
        ax += __uint_as_float(v << 16);
        ay += __uint_as_float(v & 0xffff0000u);
    }
    int deg = s1 - s0;
    float sc = 1.f / (float)(deg > 1 ? deg : 1);
    unsigned int pk = (unsigned int)f2bf(ax * sc) | ((unsigned int)f2bf(ay * sc) << 16);
    *(unsigned int*)&mean[(size_t)row * 128 + lane * 2] = pk;
}

// ---------------- fused multi-term GEMM: C = relu(sum_ph A_ph @ W_ph + bias) ----------------
// phase 0: A f32; phases 1,2: A bf16. One LDS W buffer cycled per phase.
template<int NA>
__global__ __launch_bounds__(256, 2) void gemm_fused(
    const float* __restrict__ Af, const float* __restrict__ W0,
    const ushort* __restrict__ Ab1, const float* __restrict__ W1,
    const ushort* __restrict__ Ab2, const float* __restrict__ W2,
    int M, const float* __restrict__ bias, float* __restrict__ C)
{
    __shared__ float Ws[128 * 128];   // 64 KB
    __shared__ float As[32 * 128];    // 16 KB
    const int t = threadIdx.x;
    const int row0 = blockIdx.x * 32;
    const int tx = t & 31, ty = t >> 5;
    float acc[4][4] = {};

    #pragma unroll
    for (int ph = 0; ph < NA; ++ph) {
        const float* W = (ph == 0) ? W0 : (ph == 1 ? W1 : W2);
        {
            const float4* wg = (const float4*)W;
            float4* wl = (float4*)Ws;
            #pragma unroll
            for (int i = 0; i < 16; ++i) wl[t + 256 * i] = wg[t + 256 * i];
        }
        if (ph == 0) {
            #pragma unroll
            for (int i = 0; i < 4; ++i) {
                int f = t + 256 * i;
                int rr = f >> 5, cv = f & 31;
                int rg = row0 + rr;
                float4 v = make_float4(0.f, 0.f, 0.f, 0.f);
                if (rg < M) v = ((const float4*)Af)[(size_t)rg * 32 + cv];
                *((float4*)&As[rr * 128 + cv * 4]) = v;
            }
        } else {
            const ushort* Ab = (ph == 1) ? Ab1 : Ab2;
            #pragma unroll
            for (int i = 0; i < 2; ++i) {
                int f = t + 256 * i;
                int rr = f >> 4, c16 = f & 15;
                int rg = row0 + rr;
                uint4 v = make_uint4(0u, 0u, 0u, 0u);
                if (rg < M) v = ((const uint4*)Ab)[(size_t)rg * 16 + c16];
                float* dst = &As[rr * 128 + c16 * 8];
                dst[0] = __uint_as_float(v.x << 16); dst[1] = __uint_as_float(v.x & 0xffff0000u);
                dst[2] = __uint_as_float(v.y << 16); dst[3] = __uint_as_float(v.y & 0xffff0000u);
                dst[4] = __uint_as_float(v.z << 16); dst[5] = __uint_as_float(v.z & 0xffff0000u);
                dst[6] = __uint_as_float(v.w << 16); dst[7] = __uint_as_float(v.w & 0xffff0000u);
            }
        }
        __syncthreads();

        #pragma unroll 8
        for (int k = 0; k < 128; ++k) {
            float4 w4 = *((const float4*)&Ws[k * 128 + tx * 4]);
            #pragma unroll
            for (int i = 0; i < 4; ++i) {
                float a = As[(ty * 4 + i) * 128 + k];
                acc[i][0] += a * w4.x;
                acc[i][1] += a * w4.y;
                acc[i][2] += a * w4.z;
                acc[i][3] += a * w4.w;
            }
        }
        __syncthreads();
    }

    float4 bv = *((const float4*)&bias[tx * 4]);
    #pragma unroll
    for (int i = 0; i < 4; ++i) {
        int rg = row0 + ty * 4 + i;
        if (rg >= M) continue;
        float4 res;
        res.x = fmaxf(acc[i][0] + bv.x, 0.f);
        res.y = fmaxf(acc[i][1] + bv.y, 0.f);
        res.z = fmaxf(acc[i][2] + bv.z, 0.f);
        res.w = fmaxf(acc[i][3] + bv.w, 0.f);
        ((float4*)C)[(size_t)rg * 32 + tx] = res;
    }
}

// ---------------- build C[src][g] += 1/deg[dst], g = batch[dst] ----------------
__global__ void cbuild_kernel(const int* __restrict__ src, const int* __restrict__ dst, int E,
                              const int* __restrict__ deg, const int* __restrict__ batch,
                              float* __restrict__ C)
{
    int i = blockIdx.x * blockDim.x + threadIdx.x;
    int stride = gridDim.x * blockDim.x;
    for (; i < E; i += stride) {
        int d = dst[i];
        int g = batch[d];
        float w = 1.f / (float)deg[d];
        atomicAdd(&C[(size_t)src[i] * NG + g], w);
    }
}

// ---------------- pooled agg = C^T @ X; register accumulate + plain partial stores ----------------
template<int NOUT>
__global__ __launch_bounds__(256) void poolgemm_part(
    const float* __restrict__ Ca, const float* __restrict__ Cb,
    const float* __restrict__ X, int N,
    float* __restrict__ Pa, float* __restrict__ Pb /* [NB][64][128] each */)
{
    int t = threadIdx.x;
    int c4 = t & 31;              // float4 column group
    int g0 = (t >> 5) * 8;        // 8 graphs per thread
    int rows_per = (N + gridDim.x - 1) / gridDim.x;
    int r0 = blockIdx.x * rows_per;
    int r1 = min(N, r0 + rows_per);
    float4 aa[8], ab[8];
    #pragma unroll
    for (int i = 0; i < 8; ++i) {
        aa[i] = make_float4(0.f, 0.f, 0.f, 0.f);
        if (NOUT == 2) ab[i] = make_float4(0.f, 0.f, 0.f, 0.f);
    }
    #pragma unroll 2
    for (int r = r0; r < r1; ++r) {
        float4 xv = ((const float4*)X)[(size_t)r * 32 + c4];
        const float* ca = Ca + (size_t)r * NG + g0;
        #pragma unroll
        for (int i = 0; i < 8; ++i) {
            float w = ca[i];
            aa[i].x += w * xv.x; aa[i].y += w * xv.y;
            aa[i].z += w * xv.z; aa[i].w += w * xv.w;
        }
        if (NOUT == 2) {
            const float* cb = Cb + (size_t)r * NG + g0;
            #pragma unroll
            for (int i = 0; i < 8; ++i) {
                float w = cb[i];
                ab[i].x += w * xv.x; ab[i].y += w * xv.y;
                ab[i].z += w * xv.z; ab[i].w += w * xv.w;
            }
        }
    }
    float4* pa = (float4*)(Pa + (size_t)blockIdx.x * NG * 128);
    #pragma unroll
    for (int i = 0; i < 8; ++i) pa[(g0 + i) * 32 + c4] = aa[i];
    if (NOUT == 2) {
        float4* pb = (float4*)(Pb + (size_t)blockIdx.x * NG * 128);
        #pragma unroll
        for (int i = 0; i < 8; ++i) pb[(g0 + i) * 32 + c4] = ab[i];
    }
}

// ---------------- reduce partials: 3 segments via blockIdx.y ----------------
__global__ __launch_bounds__(256) void reduceP_kernel(
    const float* __restrict__ P0, const float* __restrict__ P1, const float* __restrict__ P2,
    float* __restrict__ o0, float* __restrict__ o1, float* __restrict__ o2)
{
    const float* P = blockIdx.y == 0 ? P0 : (blockIdx.y == 1 ? P1 : P2);
    float*       o = blockIdx.y == 0 ? o0 : (blockIdx.y == 1 ? o1 : o2);
    int i = blockIdx.x * blockDim.x + threadIdx.x;   // 0..8191
    float s0 = 0.f, s1 = 0.f, s2 = 0.f, s3 = 0.f;
    #pragma unroll 4
    for (int b = 0; b < NB; b += 4) {
        s0 += P[(size_t)(b + 0) * NG * 128 + i];
        s1 += P[(size_t)(b + 1) * NG * 128 + i];
        s2 += P[(size_t)(b + 2) * NG * 128 + i];
        s3 += P[(size_t)(b + 3) * NG * 128 + i];
    }
    o[i] = (s0 + s1) + (s2 + s3);
}

// ---------------- per-graph row-sum pool, direct store (batch sorted) ----------------
__global__ __launch_bounds__(256) void rowpool_kernel(const float* __restrict__ x,
                                                      const int* __restrict__ bnd,
                                                      float* __restrict__ pool)
{
    int g = blockIdx.x;
    int lo = bnd[g], hi = bnd[g + 1];
    int col = threadIdx.x & 127, half = threadIdx.x >> 7;
    float s = 0.f;
    for (int r = lo + half; r < hi; r += 2) s += x[(size_t)r * 128 + col];
    __shared__ float ls[256];
    ls[threadIdx.x] = s;
    __syncthreads();
    if (half == 0) pool[g * 128 + col] = ls[col] + ls[128 + col];
}

// ---------------- final: layer-2 matmuls at graph level + MLP + log_softmax ----------------
__global__ __launch_bounds__(128) void final_kernel(
    const float* __restrict__ pmdu, const float* __restrict__ pmuu, const float* __restrict__ pmud,
    const float* __restrict__ pu1,  const float* __restrict__ pd1,
    const int* __restrict__ bndu, const int* __restrict__ bndd,
    const float* __restrict__ Wl2_du, const float* __restrict__ bl2_du, const float* __restrict__ Wr2_du,
    const float* __restrict__ Wl2_uu, const float* __restrict__ bl2_uu, const float* __restrict__ Wr2_uu,
    const float* __restrict__ Wl2_ud, const float* __restrict__ bl2_ud, const float* __restrict__ Wr2_ud,
    const float* __restrict__ W1, const float* __restrict__ b1,
    const float* __restrict__ W2, const float* __restrict__ b2,
    float* __restrict__ out)
{
    int g = blockIdx.x, t = threadIdx.x;
    __shared__ float smdu[128], smuu[128], smud[128], su1[128], sd1[128];
    __shared__ float xrow[256], h[128], lg[2];
    smdu[t] = pmdu[g * 128 + t];
    smuu[t] = pmuu[g * 128 + t];
    smud[t] = pmud[g * 128 + t];
    su1[t]  = pu1[g * 128 + t];
    sd1[t]  = pd1[g * 128 + t];
    __syncthreads();
    float ncu = (float)(bndu[g + 1] - bndu[g]);
    float ncd = (float)(bndd[g + 1] - bndd[g]);
    float cu = ncu > 1.f ? ncu : 1.f, cd = ncd > 1.f ? ncd : 1.f;
    float accu = ncu * (bl2_du[t] + bl2_uu[t]);
    float accd = ncd * bl2_ud[t];
    for (int k = 0; k < 128; ++k) {
        accu += smdu[k] * Wl2_du[k * 128 + t]
              + smuu[k] * Wl2_uu[k * 128 + t]
              + su1[k]  * (Wr2_du[k * 128 + t] + Wr2_uu[k * 128 + t]);
        accd += smud[k] * Wl2_ud[k * 128 + t]
              + sd1[k]  * Wr2_ud[k * 128 + t];
    }
    xrow[t]       = accu / cu;
    xrow[128 + t] = accd / cd;
    __syncthreads();
    float hh = b1[t];
    for (int k = 0; k < 256; ++k) hh += xrow[k] * W1[k * 128 + t];
    h[t] = fmaxf(hh, 0.f);
    __syncthreads();
    if (t < 2) {
        float l = b2[t];
        for (int k = 0; k < 128; ++k) l += h[k] * W2[k * 2 + t];
        lg[t] = l;
    }
    __syncthreads();
    if (t == 0) {
        float m = fmaxf(lg[0], lg[1]);
        float lse = m + logf(expf(lg[0] - m) + expf(lg[1] - m));
        out[g * 2 + 0] = lg[0] - lse;
        out[g * 2 + 1] = lg[1] - lse;
    }
}

extern "C" void kernel_launch(void* const* d_in, const int* in_sizes, int n_in,
                              void* d_out, int out_size, void* d_ws, size_t ws_size,
                              hipStream_t stream)
{
    const float* x_user = (const float*)d_in[0];
    const float* x_drug = (const float*)d_in[1];
    const int* ei_ud = (const int*)d_in[2];
    const int* ei_du = (const int*)d_in[3];
    const int* ei_uu = (const int*)d_in[4];
    const int* batch_u = (const int*)d_in[5];
    const int* batch_d = (const int*)d_in[6];
    const float* Wl1_ud = (const float*)d_in[7];  const float* bl1_ud = (const float*)d_in[8];  const float* Wr1_ud = (const float*)d_in[9];
    const float* Wl1_du = (const float*)d_in[10]; const float* bl1_du = (const float*)d_in[11]; const float* Wr1_du = (const float*)d_in[12];
    const float* Wl1_uu = (const float*)d_in[13]; const float* bl1_uu = (const float*)d_in[14]; const float* Wr1_uu = (const float*)d_in[15];
    const float* Wl2_ud = (const float*)d_in[16]; const float* bl2_ud = (const float*)d_in[17]; const float* Wr2_ud = (const float*)d_in[18];
    const float* Wl2_du = (const float*)d_in[19]; const float* bl2_du = (const float*)d_in[20]; const float* Wr2_du = (const float*)d_in[21];
    const float* Wl2_uu = (const float*)d_in[22]; const float* bl2_uu = (const float*)d_in[23]; const float* Wr2_uu = (const float*)d_in[24];
    const float* W1 = (const float*)d_in[25]; const float* b1 = (const float*)d_in[26];
    const float* W2 = (const float*)d_in[27]; const float* b2 = (const float*)d_in[28];
    (void)n_in; (void)out_size; (void)ws_size;

    const int Nu = in_sizes[0] / 128;
    const int Nd = in_sizes[1] / 128;
    const int E_ud = in_sizes[2] / 2;
    const int E_du = in_sizes[3] / 2;
    const int E_uu = in_sizes[4] / 2;

    char* ws = (char*)d_ws;
    size_t off = 0;
    auto alloc = [&](size_t bytes) -> void* {
        void* p = ws + off;
        off = (off + bytes + 255) & ~(size_t)255;
        return p;
    };
    int* csr_ud = (int*)alloc((size_t)E_ud * 4);
    int* csr_du = (int*)alloc((size_t)E_du * 4);
    int* csr_uu = (int*)alloc((size_t)E_uu * 4);
    int* rp_ud = (int*)alloc((size_t)(Nd + 1) * 4);
    int* rp_du = (int*)alloc((size_t)(Nu + 1) * 4);
    int* rp_uu = (int*)alloc((size_t)(Nu + 1) * 4);
    // deg + 3 cur buffers contiguous -> single memset
    int* deg_ud = (int*)alloc((size_t)Nd * 4);
    int* deg_du = (int*)alloc((size_t)Nu * 4);
    int* deg_uu = (int*)alloc((size_t)Nu * 4);
    int* cur0   = (int*)alloc((size_t)Nd * 4);
    int* cur1   = (int*)alloc((size_t)Nu * 4);
    int* cur2   = (int*)alloc((size_t)Nu * 4);
    char* zero_end = ws + off;
    ushort* xb_u = (ushort*)alloc((size_t)Nu * 128 * 2);
    ushort* xb_d = (ushort*)alloc((size_t)Nd * 128 * 2);
    ushort* mean_du = (ushort*)alloc((size_t)Nu * 128 * 2);   // -> C_du overlay
    ushort* mean_uu = (ushort*)alloc((size_t)Nu * 128 * 2);   // -> C_uu overlay
    ushort* mean_ud = (ushort*)alloc((size_t)Nd * 128 * 2);   // -> C_ud overlay
    float* u1 = (float*)alloc((size_t)Nu * 128 * 4);
    float* d1 = (float*)alloc((size_t)Nd * 128 * 4);
    float* pmdu = (float*)alloc(NG * 128 * 4);
    float* pmuu = (float*)alloc(NG * 128 * 4);
    float* pmud = (float*)alloc(NG * 128 * 4);
    float* pu1  = (float*)alloc(NG * 128 * 4);
    float* pd1  = (float*)alloc(NG * 128 * 4);
    int* bnd_u = (int*)alloc((NG + 1) * 4);
    int* bnd_d = (int*)alloc((NG + 1) * 4);
    float* Wr1s_u = (float*)alloc(128 * 128 * 4);
    float* b1s_u  = (float*)alloc(128 * 4);

    float* C_du = (float*)mean_du;   // [Nd,64] f32
    float* C_uu = (float*)mean_uu;   // [Nu,64]
    float* C_ud = (float*)mean_ud;   // [Nu,64]

    // partials overlay dead buffers: P1 over csr_ud..csr_du (12.8MB), P2 over xb_u..xb_d (25.6MB)
    float* P1  = (float*)csr_ud;                       // NB*8192*4 = 12.58 MB
    float* P2a = (float*)xb_u;                         // 12.58 MB
    float* P2b = (float*)xb_u + (size_t)NB * NG * 128; // 12.58 MB

    const int* dst_ud = ei_ud + E_ud;
    const int* dst_du = ei_du + E_du;
    const int* dst_uu = ei_uu + E_uu;

    // ---- CSR build ----
    hipMemsetAsync(deg_ud, 0, (size_t)(zero_end - (char*)deg_ud), stream);
    hist_kernel<<<2048, 256, 0, stream>>>(dst_ud, E_ud, deg_ud);
    hist_kernel<<<2048, 256, 0, stream>>>(dst_du, E_du, deg_du);
    hist_kernel<<<2048, 256, 0, stream>>>(dst_uu, E_uu, deg_uu);
    scan3_kernel<<<3, 1024, 0, stream>>>(deg_ud, rp_ud, Nd, deg_du, rp_du, Nu, deg_uu, rp_uu, Nu);
    fill_kernel<<<2048, 256, 0, stream>>>(ei_ud, dst_ud, E_ud, rp_ud, cur0, csr_ud);
    fill_kernel<<<2048, 256, 0, stream>>>(ei_du, dst_du, E_du, rp_du, cur1, csr_du);
    fill_kernel<<<2048, 256, 0, stream>>>(ei_uu, dst_uu, E_uu, rp_uu, cur2, csr_uu);

    // ---- graph boundaries, bf16 inputs, weight sums ----
    bounds_kernel<<<2, NG + 1, 0, stream>>>(batch_u, Nu, batch_d, Nd, bnd_u, bnd_d);
    cvt_kernel<<<(Nu * 32 + 255) / 256, 256, 0, stream>>>(x_user, xb_u, Nu * 32);
    cvt_kernel<<<(Nd * 32 + 255) / 256, 256, 0, stream>>>(x_drug, xb_d, Nd * 32);
    add2_kernel<<<64, 256, 0, stream>>>(Wr1_du, Wr1_uu, Wr1s_u, 128 * 128);
    add2_kernel<<<1, 128, 0, stream>>>(bl1_du, bl1_uu, b1s_u, 128);

    // ---- layer-1 aggregation ----
    agg_kernel<<<(Nu + 3) / 4, 256, 0, stream>>>(xb_d, rp_du, csr_du, Nu, mean_du);
    agg_kernel<<<(Nu + 3) / 4, 256, 0, stream>>>(xb_u, rp_uu, csr_uu, Nu, mean_uu);
    agg_kernel<<<(Nd + 3) / 4, 256, 0, stream>>>(xb_u, rp_ud, csr_ud, Nd, mean_ud);

    // ---- layer-1 fused GEMMs (u1: 3 terms, d1: 2 terms) ----
    int gBu = (Nu + 31) / 32, gBd = (Nd + 31) / 32;
    gemm_fused<3><<<gBu, 256, 0, stream>>>(x_user, Wr1s_u, mean_du, Wl1_du, mean_uu, Wl1_uu, Nu, b1s_u, u1);
    gemm_fused<2><<<gBd, 256, 0, stream>>>(x_drug, Wr1_ud, mean_ud, Wl1_ud, nullptr, nullptr, Nd, bl1_ud, d1);

    // ---- layer 2: pooled aggregation as C^T @ x1 (C overlays means, now dead) ----
    hipMemsetAsync(C_du, 0, (size_t)Nd * NG * 4, stream);
    hipMemsetAsync(C_uu, 0, (size_t)Nu * NG * 4, stream);
    hipMemsetAsync(C_ud, 0, (size_t)Nu * NG * 4, stream);
    cbuild_kernel<<<2048, 256, 0, stream>>>(ei_du, dst_du, E_du, deg_du, batch_u, C_du);
    cbuild_kernel<<<2048, 256, 0, stream>>>(ei_uu, dst_uu, E_uu, deg_uu, batch_u, C_uu);
    cbuild_kernel<<<2048, 256, 0, stream>>>(ei_ud, dst_ud, E_ud, deg_ud, batch_d, C_ud);

    poolgemm_part<1><<<NB, 256, 0, stream>>>(C_du, nullptr, d1, Nd, P1, nullptr);
    poolgemm_part<2><<<NB, 256, 0, stream>>>(C_uu, C_ud, u1, Nu, P2a, P2b);
    reduceP_kernel<<<dim3(32, 3), 256, 0, stream>>>(P1, P2a, P2b, pmdu, pmuu, pmud);

    // ---- root-term pools (direct store, no atomics) ----
    rowpool_kernel<<<NG, 256, 0, stream>>>(u1, bnd_u, pu1);
    rowpool_kernel<<<NG, 256, 0, stream>>>(d1, bnd_d, pd1);

    // ---- graph-level layer-2 matmuls + MLP + log_softmax ----
    final_kernel<<<NG, 128, 0, stream>>>(pmdu, pmuu, pmud, pu1, pd1, bnd_u, bnd_d,
                                         Wl2_du, bl2_du, Wr2_du,
                                         Wl2_uu, bl2_uu, Wr2_uu,
                                         Wl2_ud, bl2_ud, Wr2_ud,
                                         W1, b1, W2, b2, (float*)d_out);
}

// Round 6
// 1275.824 us; speedup vs baseline: 1.1997x; 1.1997x over previous
//
#include <hip/hip_runtime.h>

#define NG 64    // graphs

__device__ __forceinline__ ushort f2bf(float f) {
    unsigned int b = __float_as_uint(f);
    b += 0x7fffu + ((b >> 16) & 1u);   // RTNE
    return (ushort)(b >> 16);
}

// ---------------- histogram + per-edge rank (atomic returns old count) ----------------
__global__ void histrank_kernel(const int* __restrict__ idx, int n,
                                int* __restrict__ cnt, ushort* __restrict__ rank) {
    int i = blockIdx.x * blockDim.x + threadIdx.x;
    int stride = gridDim.x * blockDim.x;
    for (; i < n; i += stride) rank[i] = (ushort)atomicAdd(&cnt[idx[i]], 1);
}

// ---------------- 3-way exclusive scan -> row_ptr (shfl-based) ----------------
__global__ __launch_bounds__(1024) void scan3_kernel(
    const int* __restrict__ c0, int* __restrict__ r0, int n0,
    const int* __restrict__ c1, int* __restrict__ r1, int n1,
    const int* __restrict__ c2, int* __restrict__ r2, int n2)
{
    const int* c = blockIdx.x == 0 ? c0 : (blockIdx.x == 1 ? c1 : c2);
    int*       r = blockIdx.x == 0 ? r0 : (blockIdx.x == 1 ? r1 : r2);
    int        N = blockIdx.x == 0 ? n0 : (blockIdx.x == 1 ? n1 : n2);
    __shared__ int wsum[16];
    __shared__ int carry;
    int t = threadIdx.x, lane = t & 63, wv = t >> 6;
    if (t == 0) { carry = 0; r[0] = 0; }
    __syncthreads();
    for (int base = 0; base < N; base += 1024) {
        int i = base + t;
        int x = (i < N) ? c[i] : 0;
        #pragma unroll
        for (int off = 1; off < 64; off <<= 1) {
            int u = __shfl_up(x, off, 64);
            if (lane >= off) x += u;
        }
        if (lane == 63) wsum[wv] = x;
        __syncthreads();
        if (wv == 0 && lane < 16) {
            int v = wsum[lane];
            #pragma unroll
            for (int off = 1; off < 16; off <<= 1) {
                int u = __shfl_up(v, off, 64);
                if (lane >= off) v += u;
            }
            wsum[lane] = v;
        }
        __syncthreads();
        int add = carry + (wv > 0 ? wsum[wv - 1] : 0);
        if (i < N) r[i + 1] = x + add;
        int tot = wsum[15];
        __syncthreads();
        if (t == 0) carry += tot;
        __syncthreads();
    }
}

// ---------------- CSR fill: atomic-free via precomputed rank ----------------
__global__ void fill_kernel(const int* __restrict__ src, const int* __restrict__ dst,
                            const ushort* __restrict__ rank, int E,
                            const int* __restrict__ rp, int* __restrict__ csr)
{
    int i = blockIdx.x * blockDim.x + threadIdx.x;
    int stride = gridDim.x * blockDim.x;
    for (; i < E; i += stride) {
        int d = dst[i];
        csr[rp[d] + (int)rank[i]] = src[i];
    }
}

// ---------------- elementwise add (weight/bias sums) ----------------
__global__ void add2_kernel(const float* __restrict__ a, const float* __restrict__ b,
                            float* __restrict__ o, int n) {
    int i = blockIdx.x * blockDim.x + threadIdx.x;
    if (i < n) o[i] = a[i] + b[i];
}

// ---------------- f32 -> bf16 conversion (4 elems/thread) ----------------
__global__ void cvt_kernel(const float* __restrict__ x, ushort* __restrict__ o, int n4) {
    int i = blockIdx.x * blockDim.x + threadIdx.x;
    if (i >= n4) return;
    float4 v = ((const float4*)x)[i];
    ushort4 r;
    r.x = f2bf(v.x); r.y = f2bf(v.y); r.z = f2bf(v.z); r.w = f2bf(v.w);
    ((ushort4*)o)[i] = r;
}

// ---------------- graph boundaries via binary search (batch is sorted) ----------------
__global__ void bounds_kernel(const int* __restrict__ bu, int nu,
                              const int* __restrict__ bd, int nd,
                              int* __restrict__ bndu, int* __restrict__ bndd)
{
    const int* b = blockIdx.x == 0 ? bu : bd;
    int        n = blockIdx.x == 0 ? nu : nd;
    int*       o = blockIdx.x == 0 ? bndu : bndd;
    int g = threadIdx.x;
    if (g > NG) return;
    int lo = 0, hi = n;
    while (lo < hi) { int m = (lo + hi) >> 1; if (b[m] < g) lo = m + 1; else hi = m; }
    o[g] = lo;
}

// ---------------- CSR mean aggregation: bf16 gather -> bf16 mean rows ----------------
__global__ __launch_bounds__(256) void agg_kernel(
    const ushort* __restrict__ xb,
    const int* __restrict__ rp, const int* __restrict__ csr, int M,
    ushort* __restrict__ mean)
{
    int wave = threadIdx.x >> 6, lane = threadIdx.x & 63;
    int row = blockIdx.x * 4 + wave;
    if (row >= M) return;
    int s0 = rp[row], s1 = rp[row + 1];
    float ax = 0.f, ay = 0.f;
    int j = s0;
    for (; j + 8 <= s1; j += 8) {
        unsigned int v0 = *(const unsigned int*)&xb[(size_t)csr[j + 0] * 128 + lane * 2];
        unsigned int v1 = *(const unsigned int*)&xb[(size_t)csr[j + 1] * 128 + lane * 2];
        unsigned int v2 = *(const unsigned int*)&xb[(size_t)csr[j + 2] * 128 + lane * 2];
        unsigned int v3 = *(const unsigned int*)&xb[(size_t)csr[j + 3] * 128 + lane * 2];
        unsigned int v4 = *(const unsigned int*)&xb[(size_t)csr[j + 4] * 128 + lane * 2];
        unsigned int v5 = *(const unsigned int*)&xb[(size_t)csr[j + 5] * 128 + lane * 2];
        unsigned int v6 = *(const unsigned int*)&xb[(size_t)csr[j + 6] * 128 + lane * 2];
        unsigned int v7 = *(const unsigned int*)&xb[(size_t)csr[j + 7] * 128 + lane * 2];
        ax += __uint_as_float(v0 << 16) + __uint_as_float(v1 << 16)
            + __uint_as_float(v2 << 16) + __uint_as_float(v3 << 16)
            + __uint_as_float(v4 << 16) + __uint_as_float(v5 << 16)
            + __uint_as_float(v6 << 16) + __uint_as_float(v7 << 16);
        ay += __uint_as_float(v0 & 0xffff0000u) + __uint_as_float(v1 & 0xffff0000u)
            + __uint_as_float(v2 & 0xffff0000u) + __uint_as_float(v3 & 0xffff0000u)
            + __uint_as_float(v4 & 0xffff0000u) + __uint_as_float(v5 & 0xffff0000u)
            + __uint_as_float(v6 & 0xffff0000u) + __uint_as_float(v7 & 0xffff0000u);
    }
    for (; j < s1; ++j) {
        unsigned int v = *(const unsigned int*)&xb[(size_t)csr[j] * 128 + lane * 2];
        ax += __uint_as_float(v << 16);
        ay += __uint_as_float(v & 0xffff0000u);
    }
    int deg = s1 - s0;
    float sc = 1.f / (float)(deg > 1 ? deg : 1);
    unsigned int pk = (unsigned int)f2bf(ax * sc) | ((unsigned int)f2bf(ay * sc) << 16);
    *(unsigned int*)&mean[(size_t)row * 128 + lane * 2] = pk;
}

// ---------------- fused multi-term GEMM -> bf16 output ----------------
// phase 0: A f32; phases 1,2: A bf16. One LDS W buffer cycled per phase.
template<int NA>
__global__ __launch_bounds__(256, 2) void gemm_fused(
    const float* __restrict__ Af, const float* __restrict__ W0,
    const ushort* __restrict__ Ab1, const float* __restrict__ W1,
    const ushort* __restrict__ Ab2, const float* __restrict__ W2,
    int M, const float* __restrict__ bias, ushort* __restrict__ C)
{
    __shared__ float Ws[128 * 128];   // 64 KB
    __shared__ float As[32 * 128];    // 16 KB
    const int t = threadIdx.x;
    const int row0 = blockIdx.x * 32;
    const int tx = t & 31, ty = t >> 5;
    float acc[4][4] = {};

    #pragma unroll
    for (int ph = 0; ph < NA; ++ph) {
        const float* W = (ph == 0) ? W0 : (ph == 1 ? W1 : W2);
        {
            const float4* wg = (const float4*)W;
            float4* wl = (float4*)Ws;
            #pragma unroll
            for (int i = 0; i < 16; ++i) wl[t + 256 * i] = wg[t + 256 * i];
        }
        if (ph == 0) {
            #pragma unroll
            for (int i = 0; i < 4; ++i) {
                int f = t + 256 * i;
                int rr = f >> 5, cv = f & 31;
                int rg = row0 + rr;
                float4 v = make_float4(0.f, 0.f, 0.f, 0.f);
                if (rg < M) v = ((const float4*)Af)[(size_t)rg * 32 + cv];
                *((float4*)&As[rr * 128 + cv * 4]) = v;
            }
        } else {
            const ushort* Ab = (ph == 1) ? Ab1 : Ab2;
            #pragma unroll
            for (int i = 0; i < 2; ++i) {
                int f = t + 256 * i;
                int rr = f >> 4, c16 = f & 15;
                int rg = row0 + rr;
                uint4 v = make_uint4(0u, 0u, 0u, 0u);
                if (rg < M) v = ((const uint4*)Ab)[(size_t)rg * 16 + c16];
                float* dst = &As[rr * 128 + c16 * 8];
                dst[0] = __uint_as_float(v.x << 16); dst[1] = __uint_as_float(v.x & 0xffff0000u);
                dst[2] = __uint_as_float(v.y << 16); dst[3] = __uint_as_float(v.y & 0xffff0000u);
                dst[4] = __uint_as_float(v.z << 16); dst[5] = __uint_as_float(v.z & 0xffff0000u);
                dst[6] = __uint_as_float(v.w << 16); dst[7] = __uint_as_float(v.w & 0xffff0000u);
            }
        }
        __syncthreads();

        #pragma unroll 8
        for (int k = 0; k < 128; ++k) {
            float4 w4 = *((const float4*)&Ws[k * 128 + tx * 4]);
            #pragma unroll
            for (int i = 0; i < 4; ++i) {
                float a = As[(ty * 4 + i) * 128 + k];
                acc[i][0] += a * w4.x;
                acc[i][1] += a * w4.y;
                acc[i][2] += a * w4.z;
                acc[i][3] += a * w4.w;
            }
        }
        __syncthreads();
    }

    float4 bv = *((const float4*)&bias[tx * 4]);
    #pragma unroll
    for (int i = 0; i < 4; ++i) {
        int rg = row0 + ty * 4 + i;
        if (rg >= M) continue;
        ushort4 res;
        res.x = f2bf(fmaxf(acc[i][0] + bv.x, 0.f));
        res.y = f2bf(fmaxf(acc[i][1] + bv.y, 0.f));
        res.z = f2bf(fmaxf(acc[i][2] + bv.z, 0.f));
        res.w = f2bf(fmaxf(acc[i][3] + bv.w, 0.f));
        *((ushort4*)&C[(size_t)rg * 128 + tx * 4]) = res;
    }
}

// ---------------- fused layer-2 agg + per-graph pool ----------------
// wave walks 32 consecutive dst rows (batch sorted); register mean-sum per graph;
// flush on graph change via global atomicAdd (rare).
__global__ __launch_bounds__(256) void aggpool_kernel(
    const ushort* __restrict__ xb,          // x1 bf16 [Nsrc,128]
    const int* __restrict__ rp, const int* __restrict__ csr,
    const int* __restrict__ batch, int M,
    float* __restrict__ pool /* [64][128], pre-zeroed */)
{
    int wave = threadIdx.x >> 6, lane = threadIdx.x & 63;
    int r0 = (blockIdx.x * 4 + wave) * 32;
    if (r0 >= M) return;
    int r1 = min(M, r0 + 32);
    float ax = 0.f, ay = 0.f;
    int curg = batch[r0];
    for (int row = r0; row < r1; ++row) {
        int g = batch[row];
        if (g != curg) {
            atomicAdd(&pool[curg * 128 + lane * 2],     ax);
            atomicAdd(&pool[curg * 128 + lane * 2 + 1], ay);
            ax = 0.f; ay = 0.f; curg = g;
        }
        int s0 = rp[row], s1 = rp[row + 1];
        float sx = 0.f, sy = 0.f;
        int j = s0;
        for (; j + 8 <= s1; j += 8) {
            unsigned int v0 = *(const unsigned int*)&xb[(size_t)csr[j + 0] * 128 + lane * 2];
            unsigned int v1 = *(const unsigned int*)&xb[(size_t)csr[j + 1] * 128 + lane * 2];
            unsigned int v2 = *(const unsigned int*)&xb[(size_t)csr[j + 2] * 128 + lane * 2];
            unsigned int v3 = *(const unsigned int*)&xb[(size_t)csr[j + 3] * 128 + lane * 2];
            unsigned int v4 = *(const unsigned int*)&xb[(size_t)csr[j + 4] * 128 + lane * 2];
            unsigned int v5 = *(const unsigned int*)&xb[(size_t)csr[j + 5] * 128 + lane * 2];
            unsigned int v6 = *(const unsigned int*)&xb[(size_t)csr[j + 6] * 128 + lane * 2];
            unsigned int v7 = *(const unsigned int*)&xb[(size_t)csr[j + 7] * 128 + lane * 2];
            sx += __uint_as_float(v0 << 16) + __uint_as_float(v1 << 16)
                + __uint_as_float(v2 << 16) + __uint_as_float(v3 << 16)
                + __uint_as_float(v4 << 16) + __uint_as_float(v5 << 16)
                + __uint_as_float(v6 << 16) + __uint_as_float(v7 << 16);
            sy += __uint_as_float(v0 & 0xffff0000u) + __uint_as_float(v1 & 0xffff0000u)
                + __uint_as_float(v2 & 0xffff0000u) + __uint_as_float(v3 & 0xffff0000u)
                + __uint_as_float(v4 & 0xffff0000u) + __uint_as_float(v5 & 0xffff0000u)
                + __uint_as_float(v6 & 0xffff0000u) + __uint_as_float(v7 & 0xffff0000u);
        }
        for (; j < s1; ++j) {
            unsigned int v = *(const unsigned int*)&xb[(size_t)csr[j] * 128 + lane * 2];
            sx += __uint_as_float(v << 16);
            sy += __uint_as_float(v & 0xffff0000u);
        }
        int deg = s1 - s0;
        float sc = 1.f / (float)(deg > 1 ? deg : 1);
        ax += sx * sc; ay += sy * sc;
    }
    atomicAdd(&pool[curg * 128 + lane * 2],     ax);
    atomicAdd(&pool[curg * 128 + lane * 2 + 1], ay);
}

// ---------------- per-graph row-sum pool over bf16 x (batch sorted) ----------------
__global__ __launch_bounds__(256) void rowpool_kernel(const ushort* __restrict__ xb,
                                                      const int* __restrict__ bnd,
                                                      float* __restrict__ pool)
{
    int g = blockIdx.x;
    int lo = bnd[g], hi = bnd[g + 1];
    int c2 = threadIdx.x & 63, half = threadIdx.x >> 6;   // 64 col-pairs, 4 row stripes
    float sx = 0.f, sy = 0.f;
    for (int r = lo + half; r < hi; r += 4) {
        unsigned int v = *(const unsigned int*)&xb[(size_t)r * 128 + c2 * 2];
        sx += __uint_as_float(v << 16);
        sy += __uint_as_float(v & 0xffff0000u);
    }
    __shared__ float ls[256 * 2];
    ls[threadIdx.x * 2]     = sx;
    ls[threadIdx.x * 2 + 1] = sy;
    __syncthreads();
    if (half == 0) {
        float ox = ls[c2 * 2] + ls[(64 + c2) * 2] + ls[(128 + c2) * 2] + ls[(192 + c2) * 2];
        float oy = ls[c2 * 2 + 1] + ls[(64 + c2) * 2 + 1] + ls[(128 + c2) * 2 + 1] + ls[(192 + c2) * 2 + 1];
        pool[g * 128 + c2 * 2]     = ox;
        pool[g * 128 + c2 * 2 + 1] = oy;
    }
}

// ---------------- final: layer-2 matmuls at graph level + MLP + log_softmax ----------------
__global__ __launch_bounds__(128) void final_kernel(
    const float* __restrict__ pmdu, const float* __restrict__ pmuu, const float* __restrict__ pmud,
    const float* __restrict__ pu1,  const float* __restrict__ pd1,
    const int* __restrict__ bndu, const int* __restrict__ bndd,
    const float* __restrict__ Wl2_du, const float* __restrict__ bl2_du, const float* __restrict__ Wr2_du,
    const float* __restrict__ Wl2_uu, const float* __restrict__ bl2_uu, const float* __restrict__ Wr2_uu,
    const float* __restrict__ Wl2_ud, const float* __restrict__ bl2_ud, const float* __restrict__ Wr2_ud,
    const float* __restrict__ W1, const float* __restrict__ b1,
    const float* __restrict__ W2, const float* __restrict__ b2,
    float* __restrict__ out)
{
    int g = blockIdx.x, t = threadIdx.x;
    __shared__ float smdu[128], smuu[128], smud[128], su1[128], sd1[128];
    __shared__ float xrow[256], h[128], lg[2];
    smdu[t] = pmdu[g * 128 + t];
    smuu[t] = pmuu[g * 128 + t];
    smud[t] = pmud[g * 128 + t];
    su1[t]  = pu1[g * 128 + t];
    sd1[t]  = pd1[g * 128 + t];
    __syncthreads();
    float ncu = (float)(bndu[g + 1] - bndu[g]);
    float ncd = (float)(bndd[g + 1] - bndd[g]);
    float cu = ncu > 1.f ? ncu : 1.f, cd = ncd > 1.f ? ncd : 1.f;
    float accu = ncu * (bl2_du[t] + bl2_uu[t]);
    float accd = ncd * bl2_ud[t];
    for (int k = 0; k < 128; ++k) {
        accu += smdu[k] * Wl2_du[k * 128 + t]
              + smuu[k] * Wl2_uu[k * 128 + t]
              + su1[k]  * (Wr2_du[k * 128 + t] + Wr2_uu[k * 128 + t]);
        accd += smud[k] * Wl2_ud[k * 128 + t]
              + sd1[k]  * Wr2_ud[k * 128 + t];
    }
    xrow[t]       = accu / cu;
    xrow[128 + t] = accd / cd;
    __syncthreads();
    float hh = b1[t];
    for (int k = 0; k < 256; ++k) hh += xrow[k] * W1[k * 128 + t];
    h[t] = fmaxf(hh, 0.f);
    __syncthreads();
    if (t < 2) {
        float l = b2[t];
        for (int k = 0; k < 128; ++k) l += h[k] * W2[k * 2 + t];
        lg[t] = l;
    }
    __syncthreads();
    if (t == 0) {
        float m = fmaxf(lg[0], lg[1]);
        float lse = m + logf(expf(lg[0] - m) + expf(lg[1] - m));
        out[g * 2 + 0] = lg[0] - lse;
        out[g * 2 + 1] = lg[1] - lse;
    }
}

extern "C" void kernel_launch(void* const* d_in, const int* in_sizes, int n_in,
                              void* d_out, int out_size, void* d_ws, size_t ws_size,
                              hipStream_t stream)
{
    const float* x_user = (const float*)d_in[0];
    const float* x_drug = (const float*)d_in[1];
    const int* ei_ud = (const int*)d_in[2];
    const int* ei_du = (const int*)d_in[3];
    const int* ei_uu = (const int*)d_in[4];
    const int* batch_u = (const int*)d_in[5];
    const int* batch_d = (const int*)d_in[6];
    const float* Wl1_ud = (const float*)d_in[7];  const float* bl1_ud = (const float*)d_in[8];  const float* Wr1_ud = (const float*)d_in[9];
    const float* Wl1_du = (const float*)d_in[10]; const float* bl1_du = (const float*)d_in[11]; const float* Wr1_du = (const float*)d_in[12];
    const float* Wl1_uu = (const float*)d_in[13]; const float* bl1_uu = (const float*)d_in[14]; const float* Wr1_uu = (const float*)d_in[15];
    const float* Wl2_ud = (const float*)d_in[16]; const float* bl2_ud = (const float*)d_in[17]; const float* Wr2_ud = (const float*)d_in[18];
    const float* Wl2_du = (const float*)d_in[19]; const float* bl2_du = (const float*)d_in[20]; const float* Wr2_du = (const float*)d_in[21];
    const float* Wl2_uu = (const float*)d_in[22]; const float* bl2_uu = (const float*)d_in[23]; const float* Wr2_uu = (const float*)d_in[24];
    const float* W1 = (const float*)d_in[25]; const float* b1 = (const float*)d_in[26];
    const float* W2 = (const float*)d_in[27]; const float* b2 = (const float*)d_in[28];
    (void)n_in; (void)out_size; (void)ws_size;

    const int Nu = in_sizes[0] / 128;
    const int Nd = in_sizes[1] / 128;
    const int E_ud = in_sizes[2] / 2;
    const int E_du = in_sizes[3] / 2;
    const int E_uu = in_sizes[4] / 2;

    char* ws = (char*)d_ws;
    size_t off = 0;
    auto alloc = [&](size_t bytes) -> void* {
        void* p = ws + off;
        off = (off + bytes + 255) & ~(size_t)255;
        return p;
    };
    int* csr_ud = (int*)alloc((size_t)E_ud * 4);
    int* csr_du = (int*)alloc((size_t)E_du * 4);
    int* csr_uu = (int*)alloc((size_t)E_uu * 4);
    int* rp_ud = (int*)alloc((size_t)(Nd + 1) * 4);
    int* rp_du = (int*)alloc((size_t)(Nu + 1) * 4);
    int* rp_uu = (int*)alloc((size_t)(Nu + 1) * 4);
    // deg counters (contiguous zero region 1)
    int* deg_ud = (int*)alloc((size_t)Nd * 4);
    int* deg_du = (int*)alloc((size_t)Nu * 4);
    int* deg_uu = (int*)alloc((size_t)Nu * 4);
    char* zero1_end = ws + off;
    ushort* rank_ud = (ushort*)alloc((size_t)E_ud * 2);
    ushort* rank_du = (ushort*)alloc((size_t)E_du * 2);
    ushort* rank_uu = (ushort*)alloc((size_t)E_uu * 2);
    ushort* xb_u = (ushort*)alloc((size_t)Nu * 128 * 2);
    ushort* xb_d = (ushort*)alloc((size_t)Nd * 128 * 2);
    ushort* mean_du = (ushort*)alloc((size_t)Nu * 128 * 2);
    ushort* mean_uu = (ushort*)alloc((size_t)Nu * 128 * 2);
    ushort* mean_ud = (ushort*)alloc((size_t)Nd * 128 * 2);
    ushort* u1b = (ushort*)alloc((size_t)Nu * 128 * 2);   // layer-1 out, bf16
    ushort* d1b = (ushort*)alloc((size_t)Nd * 128 * 2);
    // pool block (contiguous zero region 2: pm* need zeroing; pu1/pd1 direct-stored)
    float* pmdu = (float*)alloc(NG * 128 * 4);
    float* pmuu = (float*)alloc(NG * 128 * 4);
    float* pmud = (float*)alloc(NG * 128 * 4);
    char* zero2_end = ws + off;
    float* pu1  = (float*)alloc(NG * 128 * 4);
    float* pd1  = (float*)alloc(NG * 128 * 4);
    int* bnd_u = (int*)alloc((NG + 1) * 4);
    int* bnd_d = (int*)alloc((NG + 1) * 4);
    float* Wr1s_u = (float*)alloc(128 * 128 * 4);
    float* b1s_u  = (float*)alloc(128 * 4);

    const int* dst_ud = ei_ud + E_ud;
    const int* dst_du = ei_du + E_du;
    const int* dst_uu = ei_uu + E_uu;

    // ---- CSR build: hist(+rank) -> scan -> atomic-free fill ----
    hipMemsetAsync(deg_ud, 0, (size_t)(zero1_end - (char*)deg_ud), stream);
    histrank_kernel<<<2048, 256, 0, stream>>>(dst_ud, E_ud, deg_ud, rank_ud);
    histrank_kernel<<<2048, 256, 0, stream>>>(dst_du, E_du, deg_du, rank_du);
    histrank_kernel<<<2048, 256, 0, stream>>>(dst_uu, E_uu, deg_uu, rank_uu);
    scan3_kernel<<<3, 1024, 0, stream>>>(deg_ud, rp_ud, Nd, deg_du, rp_du, Nu, deg_uu, rp_uu, Nu);
    fill_kernel<<<2048, 256, 0, stream>>>(ei_ud, dst_ud, rank_ud, E_ud, rp_ud, csr_ud);
    fill_kernel<<<2048, 256, 0, stream>>>(ei_du, dst_du, rank_du, E_du, rp_du, csr_du);
    fill_kernel<<<2048, 256, 0, stream>>>(ei_uu, dst_uu, rank_uu, E_uu, rp_uu, csr_uu);

    // ---- graph boundaries, bf16 inputs, weight sums ----
    bounds_kernel<<<2, NG + 1, 0, stream>>>(batch_u, Nu, batch_d, Nd, bnd_u, bnd_d);
    cvt_kernel<<<(Nu * 32 + 255) / 256, 256, 0, stream>>>(x_user, xb_u, Nu * 32);
    cvt_kernel<<<(Nd * 32 + 255) / 256, 256, 0, stream>>>(x_drug, xb_d, Nd * 32);
    add2_kernel<<<64, 256, 0, stream>>>(Wr1_du, Wr1_uu, Wr1s_u, 128 * 128);
    add2_kernel<<<1, 128, 0, stream>>>(bl1_du, bl1_uu, b1s_u, 128);

    // ---- layer-1 aggregation ----
    agg_kernel<<<(Nu + 3) / 4, 256, 0, stream>>>(xb_d, rp_du, csr_du, Nu, mean_du);
    agg_kernel<<<(Nu + 3) / 4, 256, 0, stream>>>(xb_u, rp_uu, csr_uu, Nu, mean_uu);
    agg_kernel<<<(Nd + 3) / 4, 256, 0, stream>>>(xb_u, rp_ud, csr_ud, Nd, mean_ud);

    // ---- layer-1 fused GEMMs (u1: 3 terms, d1: 2 terms) -> bf16 ----
    int gBu = (Nu + 31) / 32, gBd = (Nd + 31) / 32;
    gemm_fused<3><<<gBu, 256, 0, stream>>>(x_user, Wr1s_u, mean_du, Wl1_du, mean_uu, Wl1_uu, Nu, b1s_u, u1b);
    gemm_fused<2><<<gBd, 256, 0, stream>>>(x_drug, Wr1_ud, mean_ud, Wl1_ud, nullptr, nullptr, Nd, bl1_ud, d1b);

    // ---- layer 2: fused CSR-mean + per-graph pool (no C matrix, no big atomics) ----
    hipMemsetAsync(pmdu, 0, (size_t)(zero2_end - (char*)pmdu), stream);
    aggpool_kernel<<<(Nu + 127) / 128, 256, 0, stream>>>(d1b, rp_du, csr_du, batch_u, Nu, pmdu);
    aggpool_kernel<<<(Nu + 127) / 128, 256, 0, stream>>>(u1b, rp_uu, csr_uu, batch_u, Nu, pmuu);
    aggpool_kernel<<<(Nd + 127) / 128, 256, 0, stream>>>(u1b, rp_ud, csr_ud, batch_d, Nd, pmud);

    // ---- root-term pools (direct store) ----
    rowpool_kernel<<<NG, 256, 0, stream>>>(u1b, bnd_u, pu1);
    rowpool_kernel<<<NG, 256, 0, stream>>>(d1b, bnd_d, pd1);

    // ---- graph-level layer-2 matmuls + MLP + log_softmax ----
    final_kernel<<<NG, 128, 0, stream>>>(pmdu, pmuu, pmud, pu1, pd1, bnd_u, bnd_d,
                                         Wl2_du, bl2_du, Wr2_du,
                                         Wl2_uu, bl2_uu, Wr2_uu,
                                         Wl2_ud, bl2_ud, Wr2_ud,
                                         W1, b1, W2, b2, (float*)d_out);
}

// Round 7
// 972.490 us; speedup vs baseline: 1.5739x; 1.3119x over previous
//
#include <hip/hip_runtime.h>

#define NG 64    // graphs
#define REP 8    // pool replicas (atomic contention spread)

__device__ __forceinline__ ushort f2bf(float f) {
    unsigned int b = __float_as_uint(f);
    b += 0x7fffu + ((b >> 16) & 1u);   // RTNE
    return (ushort)(b >> 16);
}

// ---------------- histogram + per-edge rank (atomic returns old count) ----------------
__global__ void histrank_kernel(const int* __restrict__ idx, int n,
                                int* __restrict__ cnt, ushort* __restrict__ rank) {
    int i = blockIdx.x * blockDim.x + threadIdx.x;
    int stride = gridDim.x * blockDim.x;
    for (; i < n; i += stride) rank[i] = (ushort)atomicAdd(&cnt[idx[i]], 1);
}

// ---------------- 3-way exclusive scan -> row_ptr (shfl-based) ----------------
__global__ __launch_bounds__(1024) void scan3_kernel(
    const int* __restrict__ c0, int* __restrict__ r0, int n0,
    const int* __restrict__ c1, int* __restrict__ r1, int n1,
    const int* __restrict__ c2, int* __restrict__ r2, int n2)
{
    const int* c = blockIdx.x == 0 ? c0 : (blockIdx.x == 1 ? c1 : c2);
    int*       r = blockIdx.x == 0 ? r0 : (blockIdx.x == 1 ? r1 : r2);
    int        N = blockIdx.x == 0 ? n0 : (blockIdx.x == 1 ? n1 : n2);
    __shared__ int wsum[16];
    __shared__ int carry;
    int t = threadIdx.x, lane = t & 63, wv = t >> 6;
    if (t == 0) { carry = 0; r[0] = 0; }
    __syncthreads();
    for (int base = 0; base < N; base += 1024) {
        int i = base + t;
        int x = (i < N) ? c[i] : 0;
        #pragma unroll
        for (int off = 1; off < 64; off <<= 1) {
            int u = __shfl_up(x, off, 64);
            if (lane >= off) x += u;
        }
        if (lane == 63) wsum[wv] = x;
        __syncthreads();
        if (wv == 0 && lane < 16) {
            int v = wsum[lane];
            #pragma unroll
            for (int off = 1; off < 16; off <<= 1) {
                int u = __shfl_up(v, off, 64);
                if (lane >= off) v += u;
            }
            wsum[lane] = v;
        }
        __syncthreads();
        int add = carry + (wv > 0 ? wsum[wv - 1] : 0);
        if (i < N) r[i + 1] = x + add;
        int tot = wsum[15];
        __syncthreads();
        if (t == 0) carry += tot;
        __syncthreads();
    }
}

// ---------------- CSR fill: atomic-free via precomputed rank ----------------
__global__ void fill_kernel(const int* __restrict__ src, const int* __restrict__ dst,
                            const ushort* __restrict__ rank, int E,
                            const int* __restrict__ rp, int* __restrict__ csr)
{
    int i = blockIdx.x * blockDim.x + threadIdx.x;
    int stride = gridDim.x * blockDim.x;
    for (; i < E; i += stride) {
        int d = dst[i];
        csr[rp[d] + (int)rank[i]] = src[i];
    }
}

// ---------------- elementwise add (weight/bias sums) ----------------
__global__ void add2_kernel(const float* __restrict__ a, const float* __restrict__ b,
                            float* __restrict__ o, int n) {
    int i = blockIdx.x * blockDim.x + threadIdx.x;
    if (i < n) o[i] = a[i] + b[i];
}

// ---------------- f32 -> bf16 conversion (4 elems/thread) ----------------
__global__ void cvt_kernel(const float* __restrict__ x, ushort* __restrict__ o, int n4) {
    int i = blockIdx.x * blockDim.x + threadIdx.x;
    if (i >= n4) return;
    float4 v = ((const float4*)x)[i];
    ushort4 r;
    r.x = f2bf(v.x); r.y = f2bf(v.y); r.z = f2bf(v.z); r.w = f2bf(v.w);
    ((ushort4*)o)[i] = r;
}

// ---------------- graph boundaries via binary search (batch is sorted) ----------------
__global__ void bounds_kernel(const int* __restrict__ bu, int nu,
                              const int* __restrict__ bd, int nd,
                              int* __restrict__ bndu, int* __restrict__ bndd)
{
    const int* b = blockIdx.x == 0 ? bu : bd;
    int        n = blockIdx.x == 0 ? nu : nd;
    int*       o = blockIdx.x == 0 ? bndu : bndd;
    int g = threadIdx.x;
    if (g > NG) return;
    int lo = 0, hi = n;
    while (lo < hi) { int m = (lo + hi) >> 1; if (b[m] < g) lo = m + 1; else hi = m; }
    o[g] = lo;
}

// ---------------- CSR mean aggregation: bf16 gather -> bf16 mean rows ----------------
__global__ __launch_bounds__(256) void agg_kernel(
    const ushort* __restrict__ xb,
    const int* __restrict__ rp, const int* __restrict__ csr, int M,
    ushort* __restrict__ mean)
{
    int wave = threadIdx.x >> 6, lane = threadIdx.x & 63;
    int row = blockIdx.x * 4 + wave;
    if (row >= M) return;
    int s0 = rp[row], s1 = rp[row + 1];
    float ax = 0.f, ay = 0.f;
    int j = s0;
    for (; j + 8 <= s1; j += 8) {
        unsigned int v0 = *(const unsigned int*)&xb[(size_t)csr[j + 0] * 128 + lane * 2];
        unsigned int v1 = *(const unsigned int*)&xb[(size_t)csr[j + 1] * 128 + lane * 2];
        unsigned int v2 = *(const unsigned int*)&xb[(size_t)csr[j + 2] * 128 + lane * 2];
        unsigned int v3 = *(const unsigned int*)&xb[(size_t)csr[j + 3] * 128 + lane * 2];
        unsigned int v4 = *(const unsigned int*)&xb[(size_t)csr[j + 4] * 128 + lane * 2];
        unsigned int v5 = *(const unsigned int*)&xb[(size_t)csr[j + 5] * 128 + lane * 2];
        unsigned int v6 = *(const unsigned int*)&xb[(size_t)csr[j + 6] * 128 + lane * 2];
        unsigned int v7 = *(const unsigned int*)&xb[(size_t)csr[j + 7] * 128 + lane * 2];
        ax += __uint_as_float(v0 << 16) + __uint_as_float(v1 << 16)
            + __uint_as_float(v2 << 16) + __uint_as_float(v3 << 16)
            + __uint_as_float(v4 << 16) + __uint_as_float(v5 << 16)
            + __uint_as_float(v6 << 16) + __uint_as_float(v7 << 16);
        ay += __uint_as_float(v0 & 0xffff0000u) + __uint_as_float(v1 & 0xffff0000u)
            + __uint_as_float(v2 & 0xffff0000u) + __uint_as_float(v3 & 0xffff0000u)
            + __uint_as_float(v4 & 0xffff0000u) + __uint_as_float(v5 & 0xffff0000u)
            + __uint_as_float(v6 & 0xffff0000u) + __uint_as_float(v7 & 0xffff0000u);
    }
    for (; j < s1; ++j) {
        unsigned int v = *(const unsigned int*)&xb[(size_t)csr[j] * 128 + lane * 2];
        ax += __uint_as_float(v << 16);
        ay += __uint_as_float(v & 0xffff0000u);
    }
    int deg = s1 - s0;
    float sc = 1.f / (float)(deg > 1 ? deg : 1);
    unsigned int pk = (unsigned int)f2bf(ax * sc) | ((unsigned int)f2bf(ay * sc) << 16);
    *(unsigned int*)&mean[(size_t)row * 128 + lane * 2] = pk;
}

// ---------------- fused multi-term GEMM -> bf16 output ----------------
// phase 0: A f32; phases 1,2: A bf16. One LDS W buffer cycled per phase.
template<int NA>
__global__ __launch_bounds__(256, 2) void gemm_fused(
    const float* __restrict__ Af, const float* __restrict__ W0,
    const ushort* __restrict__ Ab1, const float* __restrict__ W1,
    const ushort* __restrict__ Ab2, const float* __restrict__ W2,
    int M, const float* __restrict__ bias, ushort* __restrict__ C)
{
    __shared__ float Ws[128 * 128];   // 64 KB
    __shared__ float As[32 * 128];    // 16 KB
    const int t = threadIdx.x;
    const int row0 = blockIdx.x * 32;
    const int tx = t & 31, ty = t >> 5;
    float acc[4][4] = {};

    #pragma unroll
    for (int ph = 0; ph < NA; ++ph) {
        const float* W = (ph == 0) ? W0 : (ph == 1 ? W1 : W2);
        {
            const float4* wg = (const float4*)W;
            float4* wl = (float4*)Ws;
            #pragma unroll
            for (int i = 0; i < 16; ++i) wl[t + 256 * i] = wg[t + 256 * i];
        }
        if (ph == 0) {
            #pragma unroll
            for (int i = 0; i < 4; ++i) {
                int f = t + 256 * i;
                int rr = f >> 5, cv = f & 31;
                int rg = row0 + rr;
                float4 v = make_float4(0.f, 0.f, 0.f, 0.f);
                if (rg < M) v = ((const float4*)Af)[(size_t)rg * 32 + cv];
                *((float4*)&As[rr * 128 + cv * 4]) = v;
            }
        } else {
            const ushort* Ab = (ph == 1) ? Ab1 : Ab2;
            #pragma unroll
            for (int i = 0; i < 2; ++i) {
                int f = t + 256 * i;
                int rr = f >> 4, c16 = f & 15;
                int rg = row0 + rr;
                uint4 v = make_uint4(0u, 0u, 0u, 0u);
                if (rg < M) v = ((const uint4*)Ab)[(size_t)rg * 16 + c16];
                float* dst = &As[rr * 128 + c16 * 8];
                dst[0] = __uint_as_float(v.x << 16); dst[1] = __uint_as_float(v.x & 0xffff0000u);
                dst[2] = __uint_as_float(v.y << 16); dst[3] = __uint_as_float(v.y & 0xffff0000u);
                dst[4] = __uint_as_float(v.z << 16); dst[5] = __uint_as_float(v.z & 0xffff0000u);
                dst[6] = __uint_as_float(v.w << 16); dst[7] = __uint_as_float(v.w & 0xffff0000u);
            }
        }
        __syncthreads();

        #pragma unroll 8
        for (int k = 0; k < 128; ++k) {
            float4 w4 = *((const float4*)&Ws[k * 128 + tx * 4]);
            #pragma unroll
            for (int i = 0; i < 4; ++i) {
                float a = As[(ty * 4 + i) * 128 + k];
                acc[i][0] += a * w4.x;
                acc[i][1] += a * w4.y;
                acc[i][2] += a * w4.z;
                acc[i][3] += a * w4.w;
            }
        }
        __syncthreads();
    }

    float4 bv = *((const float4*)&bias[tx * 4]);
    #pragma unroll
    for (int i = 0; i < 4; ++i) {
        int rg = row0 + ty * 4 + i;
        if (rg >= M) continue;
        ushort4 res;
        res.x = f2bf(fmaxf(acc[i][0] + bv.x, 0.f));
        res.y = f2bf(fmaxf(acc[i][1] + bv.y, 0.f));
        res.z = f2bf(fmaxf(acc[i][2] + bv.z, 0.f));
        res.w = f2bf(fmaxf(acc[i][3] + bv.w, 0.f));
        *((ushort4*)&C[(size_t)rg * 128 + tx * 4]) = res;
    }
}

// ---------------- fused layer-2 agg + per-graph pool (8 rows/wave, replicated pool) ----------------
__global__ __launch_bounds__(256) void aggpool_kernel(
    const ushort* __restrict__ xb,          // x1 bf16 [Nsrc,128]
    const int* __restrict__ rp, const int* __restrict__ csr,
    const int* __restrict__ batch, int M,
    float* __restrict__ pool /* [REP][64][128], pre-zeroed */)
{
    int wave = threadIdx.x >> 6, lane = threadIdx.x & 63;
    int r0 = (blockIdx.x * 4 + wave) * 8;
    if (r0 >= M) return;
    int r1 = min(M, r0 + 8);
    float* p = pool + (size_t)(blockIdx.x & (REP - 1)) * NG * 128;
    float ax = 0.f, ay = 0.f;
    int curg = batch[r0];
    for (int row = r0; row < r1; ++row) {
        int g = batch[row];
        if (g != curg) {
            atomicAdd(&p[curg * 128 + lane * 2],     ax);
            atomicAdd(&p[curg * 128 + lane * 2 + 1], ay);
            ax = 0.f; ay = 0.f; curg = g;
        }
        int s0 = rp[row], s1 = rp[row + 1];
        float sx = 0.f, sy = 0.f;
        int j = s0;
        for (; j + 8 <= s1; j += 8) {
            unsigned int v0 = *(const unsigned int*)&xb[(size_t)csr[j + 0] * 128 + lane * 2];
            unsigned int v1 = *(const unsigned int*)&xb[(size_t)csr[j + 1] * 128 + lane * 2];
            unsigned int v2 = *(const unsigned int*)&xb[(size_t)csr[j + 2] * 128 + lane * 2];
            unsigned int v3 = *(const unsigned int*)&xb[(size_t)csr[j + 3] * 128 + lane * 2];
            unsigned int v4 = *(const unsigned int*)&xb[(size_t)csr[j + 4] * 128 + lane * 2];
            unsigned int v5 = *(const unsigned int*)&xb[(size_t)csr[j + 5] * 128 + lane * 2];
            unsigned int v6 = *(const unsigned int*)&xb[(size_t)csr[j + 6] * 128 + lane * 2];
            unsigned int v7 = *(const unsigned int*)&xb[(size_t)csr[j + 7] * 128 + lane * 2];
            sx += __uint_as_float(v0 << 16) + __uint_as_float(v1 << 16)
                + __uint_as_float(v2 << 16) + __uint_as_float(v3 << 16)
                + __uint_as_float(v4 << 16) + __uint_as_float(v5 << 16)
                + __uint_as_float(v6 << 16) + __uint_as_float(v7 << 16);
            sy += __uint_as_float(v0 & 0xffff0000u) + __uint_as_float(v1 & 0xffff0000u)
                + __uint_as_float(v2 & 0xffff0000u) + __uint_as_float(v3 & 0xffff0000u)
                + __uint_as_float(v4 & 0xffff0000u) + __uint_as_float(v5 & 0xffff0000u)
                + __uint_as_float(v6 & 0xffff0000u) + __uint_as_float(v7 & 0xffff0000u);
        }
        for (; j < s1; ++j) {
            unsigned int v = *(const unsigned int*)&xb[(size_t)csr[j] * 128 + lane * 2];
            sx += __uint_as_float(v << 16);
            sy += __uint_as_float(v & 0xffff0000u);
        }
        int deg = s1 - s0;
        float sc = 1.f / (float)(deg > 1 ? deg : 1);
        ax += sx * sc; ay += sy * sc;
    }
    atomicAdd(&p[curg * 128 + lane * 2],     ax);
    atomicAdd(&p[curg * 128 + lane * 2 + 1], ay);
}

// ---------------- per-graph row-sum pool over bf16 x (batch sorted) ----------------
__global__ __launch_bounds__(256) void rowpool_kernel(const ushort* __restrict__ xb,
                                                      const int* __restrict__ bnd,
                                                      float* __restrict__ pool)
{
    int g = blockIdx.x;
    int lo = bnd[g], hi = bnd[g + 1];
    int c2 = threadIdx.x & 63, half = threadIdx.x >> 6;   // 64 col-pairs, 4 row stripes
    float sx = 0.f, sy = 0.f;
    for (int r = lo + half; r < hi; r += 4) {
        unsigned int v = *(const unsigned int*)&xb[(size_t)r * 128 + c2 * 2];
        sx += __uint_as_float(v << 16);
        sy += __uint_as_float(v & 0xffff0000u);
    }
    __shared__ float ls[256 * 2];
    ls[threadIdx.x * 2]     = sx;
    ls[threadIdx.x * 2 + 1] = sy;
    __syncthreads();
    if (half == 0) {
        float ox = ls[c2 * 2] + ls[(64 + c2) * 2] + ls[(128 + c2) * 2] + ls[(192 + c2) * 2];
        float oy = ls[c2 * 2 + 1] + ls[(64 + c2) * 2 + 1] + ls[(128 + c2) * 2 + 1] + ls[(192 + c2) * 2 + 1];
        pool[g * 128 + c2 * 2]     = ox;
        pool[g * 128 + c2 * 2 + 1] = oy;
    }
}

// ---------------- final: layer-2 matmuls at graph level + MLP + log_softmax ----------------
__global__ __launch_bounds__(128) void final_kernel(
    const float* __restrict__ pmdu, const float* __restrict__ pmuu, const float* __restrict__ pmud,
    const float* __restrict__ pu1,  const float* __restrict__ pd1,
    const int* __restrict__ bndu, const int* __restrict__ bndd,
    const float* __restrict__ Wl2_du, const float* __restrict__ bl2_du, const float* __restrict__ Wr2_du,
    const float* __restrict__ Wl2_uu, const float* __restrict__ bl2_uu, const float* __restrict__ Wr2_uu,
    const float* __restrict__ Wl2_ud, const float* __restrict__ bl2_ud, const float* __restrict__ Wr2_ud,
    const float* __restrict__ W1, const float* __restrict__ b1,
    const float* __restrict__ W2, const float* __restrict__ b2,
    float* __restrict__ out)
{
    int g = blockIdx.x, t = threadIdx.x;
    __shared__ float smdu[128], smuu[128], smud[128], su1[128], sd1[128];
    __shared__ float xrow[256], h[128], lg[2];
    float vdu = 0.f, vuu = 0.f, vud = 0.f;
    #pragma unroll
    for (int r = 0; r < REP; ++r) {
        vdu += pmdu[(size_t)r * NG * 128 + g * 128 + t];
        vuu += pmuu[(size_t)r * NG * 128 + g * 128 + t];
        vud += pmud[(size_t)r * NG * 128 + g * 128 + t];
    }
    smdu[t] = vdu;
    smuu[t] = vuu;
    smud[t] = vud;
    su1[t]  = pu1[g * 128 + t];
    sd1[t]  = pd1[g * 128 + t];
    __syncthreads();
    float ncu = (float)(bndu[g + 1] - bndu[g]);
    float ncd = (float)(bndd[g + 1] - bndd[g]);
    float cu = ncu > 1.f ? ncu : 1.f, cd = ncd > 1.f ? ncd : 1.f;
    float accu = ncu * (bl2_du[t] + bl2_uu[t]);
    float accd = ncd * bl2_ud[t];
    for (int k = 0; k < 128; ++k) {
        accu += smdu[k] * Wl2_du[k * 128 + t]
              + smuu[k] * Wl2_uu[k * 128 + t]
              + su1[k]  * (Wr2_du[k * 128 + t] + Wr2_uu[k * 128 + t]);
        accd += smud[k] * Wl2_ud[k * 128 + t]
              + sd1[k]  * Wr2_ud[k * 128 + t];
    }
    xrow[t]       = accu / cu;
    xrow[128 + t] = accd / cd;
    __syncthreads();
    float hh = b1[t];
    for (int k = 0; k < 256; ++k) hh += xrow[k] * W1[k * 128 + t];
    h[t] = fmaxf(hh, 0.f);
    __syncthreads();
    if (t < 2) {
        float l = b2[t];
        for (int k = 0; k < 128; ++k) l += h[k] * W2[k * 2 + t];
        lg[t] = l;
    }
    __syncthreads();
    if (t == 0) {
        float m = fmaxf(lg[0], lg[1]);
        float lse = m + logf(expf(lg[0] - m) + expf(lg[1] - m));
        out[g * 2 + 0] = lg[0] - lse;
        out[g * 2 + 1] = lg[1] - lse;
    }
}

extern "C" void kernel_launch(void* const* d_in, const int* in_sizes, int n_in,
                              void* d_out, int out_size, void* d_ws, size_t ws_size,
                              hipStream_t stream)
{
    const float* x_user = (const float*)d_in[0];
    const float* x_drug = (const float*)d_in[1];
    const int* ei_ud = (const int*)d_in[2];
    const int* ei_du = (const int*)d_in[3];
    const int* ei_uu = (const int*)d_in[4];
    const int* batch_u = (const int*)d_in[5];
    const int* batch_d = (const int*)d_in[6];
    const float* Wl1_ud = (const float*)d_in[7];  const float* bl1_ud = (const float*)d_in[8];  const float* Wr1_ud = (const float*)d_in[9];
    const float* Wl1_du = (const float*)d_in[10]; const float* bl1_du = (const float*)d_in[11]; const float* Wr1_du = (const float*)d_in[12];
    const float* Wl1_uu = (const float*)d_in[13]; const float* bl1_uu = (const float*)d_in[14]; const float* Wr1_uu = (const float*)d_in[15];
    const float* Wl2_ud = (const float*)d_in[16]; const float* bl2_ud = (const float*)d_in[17]; const float* Wr2_ud = (const float*)d_in[18];
    const float* Wl2_du = (const float*)d_in[19]; const float* bl2_du = (const float*)d_in[20]; const float* Wr2_du = (const float*)d_in[21];
    const float* Wl2_uu = (const float*)d_in[22]; const float* bl2_uu = (const float*)d_in[23]; const float* Wr2_uu = (const float*)d_in[24];
    const float* W1 = (const float*)d_in[25]; const float* b1 = (const float*)d_in[26];
    const float* W2 = (const float*)d_in[27]; const float* b2 = (const float*)d_in[28];
    (void)n_in; (void)out_size; (void)ws_size;

    const int Nu = in_sizes[0] / 128;
    const int Nd = in_sizes[1] / 128;
    const int E_ud = in_sizes[2] / 2;
    const int E_du = in_sizes[3] / 2;
    const int E_uu = in_sizes[4] / 2;

    char* ws = (char*)d_ws;
    size_t off = 0;
    auto alloc = [&](size_t bytes) -> void* {
        void* p = ws + off;
        off = (off + bytes + 255) & ~(size_t)255;
        return p;
    };
    int* csr_ud = (int*)alloc((size_t)E_ud * 4);
    int* csr_du = (int*)alloc((size_t)E_du * 4);
    int* csr_uu = (int*)alloc((size_t)E_uu * 4);
    int* rp_ud = (int*)alloc((size_t)(Nd + 1) * 4);
    int* rp_du = (int*)alloc((size_t)(Nu + 1) * 4);
    int* rp_uu = (int*)alloc((size_t)(Nu + 1) * 4);
    // deg counters (contiguous zero region 1)
    int* deg_ud = (int*)alloc((size_t)Nd * 4);
    int* deg_du = (int*)alloc((size_t)Nu * 4);
    int* deg_uu = (int*)alloc((size_t)Nu * 4);
    char* zero1_end = ws + off;
    ushort* rank_ud = (ushort*)alloc((size_t)E_ud * 2);
    ushort* rank_du = (ushort*)alloc((size_t)E_du * 2);
    ushort* rank_uu = (ushort*)alloc((size_t)E_uu * 2);
    ushort* xb_u = (ushort*)alloc((size_t)Nu * 128 * 2);
    ushort* xb_d = (ushort*)alloc((size_t)Nd * 128 * 2);
    ushort* mean_du = (ushort*)alloc((size_t)Nu * 128 * 2);
    ushort* mean_uu = (ushort*)alloc((size_t)Nu * 128 * 2);
    ushort* mean_ud = (ushort*)alloc((size_t)Nd * 128 * 2);
    ushort* u1b = (ushort*)alloc((size_t)Nu * 128 * 2);   // layer-1 out, bf16
    ushort* d1b = (ushort*)alloc((size_t)Nd * 128 * 2);
    // pool block (contiguous zero region 2: replicated pm*)
    float* pmdu = (float*)alloc((size_t)REP * NG * 128 * 4);
    float* pmuu = (float*)alloc((size_t)REP * NG * 128 * 4);
    float* pmud = (float*)alloc((size_t)REP * NG * 128 * 4);
    char* zero2_end = ws + off;
    float* pu1  = (float*)alloc(NG * 128 * 4);
    float* pd1  = (float*)alloc(NG * 128 * 4);
    int* bnd_u = (int*)alloc((NG + 1) * 4);
    int* bnd_d = (int*)alloc((NG + 1) * 4);
    float* Wr1s_u = (float*)alloc(128 * 128 * 4);
    float* b1s_u  = (float*)alloc(128 * 4);

    const int* dst_ud = ei_ud + E_ud;
    const int* dst_du = ei_du + E_du;
    const int* dst_uu = ei_uu + E_uu;

    // ---- CSR build: hist(+rank) -> scan -> atomic-free fill ----
    hipMemsetAsync(deg_ud, 0, (size_t)(zero1_end - (char*)deg_ud), stream);
    histrank_kernel<<<2048, 256, 0, stream>>>(dst_ud, E_ud, deg_ud, rank_ud);
    histrank_kernel<<<2048, 256, 0, stream>>>(dst_du, E_du, deg_du, rank_du);
    histrank_kernel<<<2048, 256, 0, stream>>>(dst_uu, E_uu, deg_uu, rank_uu);
    scan3_kernel<<<3, 1024, 0, stream>>>(deg_ud, rp_ud, Nd, deg_du, rp_du, Nu, deg_uu, rp_uu, Nu);
    fill_kernel<<<2048, 256, 0, stream>>>(ei_ud, dst_ud, rank_ud, E_ud, rp_ud, csr_ud);
    fill_kernel<<<2048, 256, 0, stream>>>(ei_du, dst_du, rank_du, E_du, rp_du, csr_du);
    fill_kernel<<<2048, 256, 0, stream>>>(ei_uu, dst_uu, rank_uu, E_uu, rp_uu, csr_uu);

    // ---- graph boundaries, bf16 inputs, weight sums ----
    bounds_kernel<<<2, NG + 1, 0, stream>>>(batch_u, Nu, batch_d, Nd, bnd_u, bnd_d);
    cvt_kernel<<<(Nu * 32 + 255) / 256, 256, 0, stream>>>(x_user, xb_u, Nu * 32);
    cvt_kernel<<<(Nd * 32 + 255) / 256, 256, 0, stream>>>(x_drug, xb_d, Nd * 32);
    add2_kernel<<<64, 256, 0, stream>>>(Wr1_du, Wr1_uu, Wr1s_u, 128 * 128);
    add2_kernel<<<1, 128, 0, stream>>>(bl1_du, bl1_uu, b1s_u, 128);

    // ---- layer-1 aggregation ----
    agg_kernel<<<(Nu + 3) / 4, 256, 0, stream>>>(xb_d, rp_du, csr_du, Nu, mean_du);
    agg_kernel<<<(Nu + 3) / 4, 256, 0, stream>>>(xb_u, rp_uu, csr_uu, Nu, mean_uu);
    agg_kernel<<<(Nd + 3) / 4, 256, 0, stream>>>(xb_u, rp_ud, csr_ud, Nd, mean_ud);

    // ---- layer-1 fused GEMMs (u1: 3 terms, d1: 2 terms) -> bf16 ----
    int gBu = (Nu + 31) / 32, gBd = (Nd + 31) / 32;
    gemm_fused<3><<<gBu, 256, 0, stream>>>(x_user, Wr1s_u, mean_du, Wl1_du, mean_uu, Wl1_uu, Nu, b1s_u, u1b);
    gemm_fused<2><<<gBd, 256, 0, stream>>>(x_drug, Wr1_ud, mean_ud, Wl1_ud, nullptr, nullptr, Nd, bl1_ud, d1b);

    // ---- layer 2: fused CSR-mean + per-graph pool (8 rows/wave, replicated pools) ----
    hipMemsetAsync(pmdu, 0, (size_t)(zero2_end - (char*)pmdu), stream);
    aggpool_kernel<<<(Nu + 31) / 32, 256, 0, stream>>>(d1b, rp_du, csr_du, batch_u, Nu, pmdu);
    aggpool_kernel<<<(Nu + 31) / 32, 256, 0, stream>>>(u1b, rp_uu, csr_uu, batch_u, Nu, pmuu);
    aggpool_kernel<<<(Nd + 31) / 32, 256, 0, stream>>>(u1b, rp_ud, csr_ud, batch_d, Nd, pmud);

    // ---- root-term pools (direct store) ----
    rowpool_kernel<<<NG, 256, 0, stream>>>(u1b, bnd_u, pu1);
    rowpool_kernel<<<NG, 256, 0, stream>>>(d1b, bnd_d, pd1);

    // ---- graph-level layer-2 matmuls + MLP + log_softmax ----
    final_kernel<<<NG, 128, 0, stream>>>(pmdu, pmuu, pmud, pu1, pd1, bnd_u, bnd_d,
                                         Wl2_du, bl2_du, Wr2_du,
                                         Wl2_uu, bl2_uu, Wr2_uu,
                                         Wl2_ud, bl2_ud, Wr2_ud,
                                         W1, b1, W2, b2, (float*)d_out);
}

// Round 8
// 942.313 us; speedup vs baseline: 1.6243x; 1.0320x over previous
//
#include <hip/hip_runtime.h>

#define NG 64    // graphs
#define REP 8    // pool replicas (atomic contention spread)

typedef __bf16 bf16x8 __attribute__((ext_vector_type(8)));
typedef float  f32x4  __attribute__((ext_vector_type(4)));

__device__ __forceinline__ ushort f2bf(float f) {
    unsigned int b = __float_as_uint(f);
    b += 0x7fffu + ((b >> 16) & 1u);   // RTNE
    return (ushort)(b >> 16);
}

// ---------------- histogram + per-edge rank (atomic returns old count) ----------------
__global__ void histrank_kernel(const int* __restrict__ idx, int n,
                                int* __restrict__ cnt, ushort* __restrict__ rank) {
    int i = blockIdx.x * blockDim.x + threadIdx.x;
    int stride = gridDim.x * blockDim.x;
    for (; i < n; i += stride) rank[i] = (ushort)atomicAdd(&cnt[idx[i]], 1);
}

// ---------------- 3-way exclusive scan -> row_ptr (shfl-based) ----------------
__global__ __launch_bounds__(1024) void scan3_kernel(
    const int* __restrict__ c0, int* __restrict__ r0, int n0,
    const int* __restrict__ c1, int* __restrict__ r1, int n1,
    const int* __restrict__ c2, int* __restrict__ r2, int n2)
{
    const int* c = blockIdx.x == 0 ? c0 : (blockIdx.x == 1 ? c1 : c2);
    int*       r = blockIdx.x == 0 ? r0 : (blockIdx.x == 1 ? r1 : r2);
    int        N = blockIdx.x == 0 ? n0 : (blockIdx.x == 1 ? n1 : n2);
    __shared__ int wsum[16];
    __shared__ int carry;
    int t = threadIdx.x, lane = t & 63, wv = t >> 6;
    if (t == 0) { carry = 0; r[0] = 0; }
    __syncthreads();
    for (int base = 0; base < N; base += 1024) {
        int i = base + t;
        int x = (i < N) ? c[i] : 0;
        #pragma unroll
        for (int off = 1; off < 64; off <<= 1) {
            int u = __shfl_up(x, off, 64);
            if (lane >= off) x += u;
        }
        if (lane == 63) wsum[wv] = x;
        __syncthreads();
        if (wv == 0 && lane < 16) {
            int v = wsum[lane];
            #pragma unroll
            for (int off = 1; off < 16; off <<= 1) {
                int u = __shfl_up(v, off, 64);
                if (lane >= off) v += u;
            }
            wsum[lane] = v;
        }
        __syncthreads();
        int add = carry + (wv > 0 ? wsum[wv - 1] : 0);
        if (i < N) r[i + 1] = x + add;
        int tot = wsum[15];
        __syncthreads();
        if (t == 0) carry += tot;
        __syncthreads();
    }
}

// ---------------- CSR fill: atomic-free via precomputed rank ----------------
__global__ void fill_kernel(const int* __restrict__ src, const int* __restrict__ dst,
                            const ushort* __restrict__ rank, int E,
                            const int* __restrict__ rp, int* __restrict__ csr)
{
    int i = blockIdx.x * blockDim.x + threadIdx.x;
    int stride = gridDim.x * blockDim.x;
    for (; i < E; i += stride) {
        int d = dst[i];
        csr[rp[d] + (int)rank[i]] = src[i];
    }
}

// ---------------- elementwise add (bias sums) ----------------
__global__ void add2_kernel(const float* __restrict__ a, const float* __restrict__ b,
                            float* __restrict__ o, int n) {
    int i = blockIdx.x * blockDim.x + threadIdx.x;
    if (i < n) o[i] = a[i] + b[i];
}

// ---------------- f32 -> bf16 conversion (4 elems/thread) ----------------
__global__ void cvt_kernel(const float* __restrict__ x, ushort* __restrict__ o, int n4) {
    int i = blockIdx.x * blockDim.x + threadIdx.x;
    if (i >= n4) return;
    float4 v = ((const float4*)x)[i];
    ushort4 r;
    r.x = f2bf(v.x); r.y = f2bf(v.y); r.z = f2bf(v.z); r.w = f2bf(v.w);
    ((ushort4*)o)[i] = r;
}

// ---------------- weight prep: Wt[n][k] = bf16(Wa[k][n] (+Wb[k][n])) , 5 jobs ----------------
__global__ void wprep_kernel(
    const float* __restrict__ Wa0, const float* __restrict__ Wb0, ushort* __restrict__ Wt0,
    const float* __restrict__ Wa1, ushort* __restrict__ Wt1,
    const float* __restrict__ Wa2, ushort* __restrict__ Wt2,
    const float* __restrict__ Wa3, ushort* __restrict__ Wt3,
    const float* __restrict__ Wa4, ushort* __restrict__ Wt4)
{
    const float* Wa; const float* Wb = nullptr; ushort* Wt;
    switch (blockIdx.x) {
        case 0: Wa = Wa0; Wb = Wb0; Wt = Wt0; break;
        case 1: Wa = Wa1; Wt = Wt1; break;
        case 2: Wa = Wa2; Wt = Wt2; break;
        case 3: Wa = Wa3; Wt = Wt3; break;
        default: Wa = Wa4; Wt = Wt4; break;
    }
    for (int idx = threadIdx.x; idx < 128 * 128; idx += 256) {
        int n = idx >> 7, k = idx & 127;
        float v = Wa[k * 128 + n];
        if (Wb) v += Wb[k * 128 + n];
        Wt[idx] = f2bf(v);
    }
}

// ---------------- graph boundaries via binary search (batch is sorted) ----------------
__global__ void bounds_kernel(const int* __restrict__ bu, int nu,
                              const int* __restrict__ bd, int nd,
                              int* __restrict__ bndu, int* __restrict__ bndd)
{
    const int* b = blockIdx.x == 0 ? bu : bd;
    int        n = blockIdx.x == 0 ? nu : nd;
    int*       o = blockIdx.x == 0 ? bndu : bndd;
    int g = threadIdx.x;
    if (g > NG) return;
    int lo = 0, hi = n;
    while (lo < hi) { int m = (lo + hi) >> 1; if (b[m] < g) lo = m + 1; else hi = m; }
    o[g] = lo;
}

// ---------------- CSR mean aggregation: bf16 gather -> bf16 mean rows ----------------
__global__ __launch_bounds__(256) void agg_kernel(
    const ushort* __restrict__ xb,
    const int* __restrict__ rp, const int* __restrict__ csr, int M,
    ushort* __restrict__ mean)
{
    int wave = threadIdx.x >> 6, lane = threadIdx.x & 63;
    int row = blockIdx.x * 4 + wave;
    if (row >= M) return;
    int s0 = rp[row], s1 = rp[row + 1];
    float ax = 0.f, ay = 0.f;
    int j = s0;
    for (; j + 8 <= s1; j += 8) {
        unsigned int v0 = *(const unsigned int*)&xb[(size_t)csr[j + 0] * 128 + lane * 2];
        unsigned int v1 = *(const unsigned int*)&xb[(size_t)csr[j + 1] * 128 + lane * 2];
        unsigned int v2 = *(const unsigned int*)&xb[(size_t)csr[j + 2] * 128 + lane * 2];
        unsigned int v3 = *(const unsigned int*)&xb[(size_t)csr[j + 3] * 128 + lane * 2];
        unsigned int v4 = *(const unsigned int*)&xb[(size_t)csr[j + 4] * 128 + lane * 2];
        unsigned int v5 = *(const unsigned int*)&xb[(size_t)csr[j + 5] * 128 + lane * 2];
        unsigned int v6 = *(const unsigned int*)&xb[(size_t)csr[j + 6] * 128 + lane * 2];
        unsigned int v7 = *(const unsigned int*)&xb[(size_t)csr[j + 7] * 128 + lane * 2];
        ax += __uint_as_float(v0 << 16) + __uint_as_float(v1 << 16)
            + __uint_as_float(v2 << 16) + __uint_as_float(v3 << 16)
            + __uint_as_float(v4 << 16) + __uint_as_float(v5 << 16)
            + __uint_as_float(v6 << 16) + __uint_as_float(v7 << 16);
        ay += __uint_as_float(v0 & 0xffff0000u) + __uint_as_float(v1 & 0xffff0000u)
            + __uint_as_float(v2 & 0xffff0000u) + __uint_as_float(v3 & 0xffff0000u)
            + __uint_as_float(v4 & 0xffff0000u) + __uint_as_float(v5 & 0xffff0000u)
            + __uint_as_float(v6 & 0xffff0000u) + __uint_as_float(v7 & 0xffff0000u);
    }
    for (; j < s1; ++j) {
        unsigned int v = *(const unsigned int*)&xb[(size_t)csr[j] * 128 + lane * 2];
        ax += __uint_as_float(v << 16);
        ay += __uint_as_float(v & 0xffff0000u);
    }
    int deg = s1 - s0;
    float sc = 1.f / (float)(deg > 1 ? deg : 1);
    unsigned int pk = (unsigned int)f2bf(ax * sc) | ((unsigned int)f2bf(ay * sc) << 16);
    *(unsigned int*)&mean[(size_t)row * 128 + lane * 2] = pk;
}

// ---------------- MFMA multi-term GEMM: C = relu(sum A_t @ W_t + bias) -> bf16 ----------------
// A_t: [M,128] bf16 row-major; Wt_t: [128 n][128 k] bf16 (pre-transposed).
// mfma_f32_16x16x32_bf16: A row=lane&15, k=(lane>>4)*8+i; D col=lane&15, row=(lane>>4)*4+reg.
template<int NA>
__global__ __launch_bounds__(256) void gemm_mfma(
    const ushort* __restrict__ A0, const ushort* __restrict__ A1, const ushort* __restrict__ A2,
    const ushort* __restrict__ Wt0, const ushort* __restrict__ Wt1, const ushort* __restrict__ Wt2,
    int M, const float* __restrict__ bias, ushort* __restrict__ C)
{
    int wave = threadIdx.x >> 6, lane = threadIdx.x & 63;
    int row0 = blockIdx.x * 64 + wave * 16;
    int r  = lane & 15;      // A-row / D-col component
    int kg = lane >> 4;      // k-group 0..3
    f32x4 acc[8];
    #pragma unroll
    for (int nt = 0; nt < 8; ++nt) acc[nt] = (f32x4){0.f, 0.f, 0.f, 0.f};

    int arow = row0 + r;
    int arow_c = arow < M ? arow : 0;   // clamp; invalid D rows are never stored
    #pragma unroll
    for (int term = 0; term < NA; ++term) {
        const ushort* A  = (term == 0) ? A0  : (term == 1 ? A1  : A2);
        const ushort* Wt = (term == 0) ? Wt0 : (term == 1 ? Wt1 : Wt2);
        #pragma unroll
        for (int kk = 0; kk < 4; ++kk) {
            bf16x8 a = *(const bf16x8*)&A[(size_t)arow_c * 128 + kk * 32 + kg * 8];
            #pragma unroll
            for (int nt = 0; nt < 8; ++nt) {
                bf16x8 b = *(const bf16x8*)&Wt[(size_t)(nt * 16 + r) * 128 + kk * 32 + kg * 8];
                acc[nt] = __builtin_amdgcn_mfma_f32_16x16x32_bf16(a, b, acc[nt], 0, 0, 0);
            }
        }
    }

    #pragma unroll
    for (int nt = 0; nt < 8; ++nt) {
        int col = nt * 16 + r;
        float bv = bias[col];
        #pragma unroll
        for (int j = 0; j < 4; ++j) {
            int orow = row0 + kg * 4 + j;
            if (orow < M) {
                float v = fmaxf(acc[nt][j] + bv, 0.f);
                C[(size_t)orow * 128 + col] = f2bf(v);
            }
        }
    }
}

// ---------------- fused layer-2 agg + per-graph pool (8 rows/wave, replicated pool) ----------------
__global__ __launch_bounds__(256) void aggpool_kernel(
    const ushort* __restrict__ xb,
    const int* __restrict__ rp, const int* __restrict__ csr,
    const int* __restrict__ batch, int M,
    float* __restrict__ pool /* [REP][64][128], pre-zeroed */)
{
    int wave = threadIdx.x >> 6, lane = threadIdx.x & 63;
    int r0 = (blockIdx.x * 4 + wave) * 8;
    if (r0 >= M) return;
    int r1 = min(M, r0 + 8);
    float* p = pool + (size_t)(blockIdx.x & (REP - 1)) * NG * 128;
    float ax = 0.f, ay = 0.f;
    int curg = batch[r0];
    for (int row = r0; row < r1; ++row) {
        int g = batch[row];
        if (g != curg) {
            atomicAdd(&p[curg * 128 + lane * 2],     ax);
            atomicAdd(&p[curg * 128 + lane * 2 + 1], ay);
            ax = 0.f; ay = 0.f; curg = g;
        }
        int s0 = rp[row], s1 = rp[row + 1];
        float sx = 0.f, sy = 0.f;
        int j = s0;
        for (; j + 8 <= s1; j += 8) {
            unsigned int v0 = *(const unsigned int*)&xb[(size_t)csr[j + 0] * 128 + lane * 2];
            unsigned int v1 = *(const unsigned int*)&xb[(size_t)csr[j + 1] * 128 + lane * 2];
            unsigned int v2 = *(const unsigned int*)&xb[(size_t)csr[j + 2] * 128 + lane * 2];
            unsigned int v3 = *(const unsigned int*)&xb[(size_t)csr[j + 3] * 128 + lane * 2];
            unsigned int v4 = *(const unsigned int*)&xb[(size_t)csr[j + 4] * 128 + lane * 2];
            unsigned int v5 = *(const unsigned int*)&xb[(size_t)csr[j + 5] * 128 + lane * 2];
            unsigned int v6 = *(const unsigned int*)&xb[(size_t)csr[j + 6] * 128 + lane * 2];
            unsigned int v7 = *(const unsigned int*)&xb[(size_t)csr[j + 7] * 128 + lane * 2];
            sx += __uint_as_float(v0 << 16) + __uint_as_float(v1 << 16)
                + __uint_as_float(v2 << 16) + __uint_as_float(v3 << 16)
                + __uint_as_float(v4 << 16) + __uint_as_float(v5 << 16)
                + __uint_as_float(v6 << 16) + __uint_as_float(v7 << 16);
            sy += __uint_as_float(v0 & 0xffff0000u) + __uint_as_float(v1 & 0xffff0000u)
                + __uint_as_float(v2 & 0xffff0000u) + __uint_as_float(v3 & 0xffff0000u)
                + __uint_as_float(v4 & 0xffff0000u) + __uint_as_float(v5 & 0xffff0000u)
                + __uint_as_float(v6 & 0xffff0000u) + __uint_as_float(v7 & 0xffff0000u);
        }
        for (; j < s1; ++j) {
            unsigned int v = *(const unsigned int*)&xb[(size_t)csr[j] * 128 + lane * 2];
            sx += __uint_as_float(v << 16);
            sy += __uint_as_float(v & 0xffff0000u);
        }
        int deg = s1 - s0;
        float sc = 1.f / (float)(deg > 1 ? deg : 1);
        ax += sx * sc; ay += sy * sc;
    }
    atomicAdd(&p[curg * 128 + lane * 2],     ax);
    atomicAdd(&p[curg * 128 + lane * 2 + 1], ay);
}

// ---------------- per-graph row-sum pool over bf16 x (batch sorted) ----------------
__global__ __launch_bounds__(256) void rowpool_kernel(const ushort* __restrict__ xb,
                                                      const int* __restrict__ bnd,
                                                      float* __restrict__ pool)
{
    int g = blockIdx.x;
    int lo = bnd[g], hi = bnd[g + 1];
    int c2 = threadIdx.x & 63, half = threadIdx.x >> 6;
    float sx = 0.f, sy = 0.f;
    for (int r = lo + half; r < hi; r += 4) {
        unsigned int v = *(const unsigned int*)&xb[(size_t)r * 128 + c2 * 2];
        sx += __uint_as_float(v << 16);
        sy += __uint_as_float(v & 0xffff0000u);
    }
    __shared__ float ls[256 * 2];
    ls[threadIdx.x * 2]     = sx;
    ls[threadIdx.x * 2 + 1] = sy;
    __syncthreads();
    if (half == 0) {
        float ox = ls[c2 * 2] + ls[(64 + c2) * 2] + ls[(128 + c2) * 2] + ls[(192 + c2) * 2];
        float oy = ls[c2 * 2 + 1] + ls[(64 + c2) * 2 + 1] + ls[(128 + c2) * 2 + 1] + ls[(192 + c2) * 2 + 1];
        pool[g * 128 + c2 * 2]     = ox;
        pool[g * 128 + c2 * 2 + 1] = oy;
    }
}

// ---------------- final: layer-2 matmuls at graph level + MLP + log_softmax ----------------
__global__ __launch_bounds__(128) void final_kernel(
    const float* __restrict__ pmdu, const float* __restrict__ pmuu, const float* __restrict__ pmud,
    const float* __restrict__ pu1,  const float* __restrict__ pd1,
    const int* __restrict__ bndu, const int* __restrict__ bndd,
    const float* __restrict__ Wl2_du, const float* __restrict__ bl2_du, const float* __restrict__ Wr2_du,
    const float* __restrict__ Wl2_uu, const float* __restrict__ bl2_uu, const float* __restrict__ Wr2_uu,
    const float* __restrict__ Wl2_ud, const float* __restrict__ bl2_ud, const float* __restrict__ Wr2_ud,
    const float* __restrict__ W1, const float* __restrict__ b1,
    const float* __restrict__ W2, const float* __restrict__ b2,
    float* __restrict__ out)
{
    int g = blockIdx.x, t = threadIdx.x;
    __shared__ float smdu[128], smuu[128], smud[128], su1[128], sd1[128];
    __shared__ float xrow[256], h[128], lg[2];
    float vdu = 0.f, vuu = 0.f, vud = 0.f;
    #pragma unroll
    for (int r = 0; r < REP; ++r) {
        vdu += pmdu[(size_t)r * NG * 128 + g * 128 + t];
        vuu += pmuu[(size_t)r * NG * 128 + g * 128 + t];
        vud += pmud[(size_t)r * NG * 128 + g * 128 + t];
    }
    smdu[t] = vdu;
    smuu[t] = vuu;
    smud[t] = vud;
    su1[t]  = pu1[g * 128 + t];
    sd1[t]  = pd1[g * 128 + t];
    __syncthreads();
    float ncu = (float)(bndu[g + 1] - bndu[g]);
    float ncd = (float)(bndd[g + 1] - bndd[g]);
    float cu = ncu > 1.f ? ncu : 1.f, cd = ncd > 1.f ? ncd : 1.f;
    float accu = ncu * (bl2_du[t] + bl2_uu[t]);
    float accd = ncd * bl2_ud[t];
    for (int k = 0; k < 128; ++k) {
        accu += smdu[k] * Wl2_du[k * 128 + t]
              + smuu[k] * Wl2_uu[k * 128 + t]
              + su1[k]  * (Wr2_du[k * 128 + t] + Wr2_uu[k * 128 + t]);
        accd += smud[k] * Wl2_ud[k * 128 + t]
              + sd1[k]  * Wr2_ud[k * 128 + t];
    }
    xrow[t]       = accu / cu;
    xrow[128 + t] = accd / cd;
    __syncthreads();
    float hh = b1[t];
    for (int k = 0; k < 256; ++k) hh += xrow[k] * W1[k * 128 + t];
    h[t] = fmaxf(hh, 0.f);
    __syncthreads();
    if (t < 2) {
        float l = b2[t];
        for (int k = 0; k < 128; ++k) l += h[k] * W2[k * 2 + t];
        lg[t] = l;
    }
    __syncthreads();
    if (t == 0) {
        float m = fmaxf(lg[0], lg[1]);
        float lse = m + logf(expf(lg[0] - m) + expf(lg[1] - m));
        out[g * 2 + 0] = lg[0] - lse;
        out[g * 2 + 1] = lg[1] - lse;
    }
}

extern "C" void kernel_launch(void* const* d_in, const int* in_sizes, int n_in,
                              void* d_out, int out_size, void* d_ws, size_t ws_size,
                              hipStream_t stream)
{
    const float* x_user = (const float*)d_in[0];
    const float* x_drug = (const float*)d_in[1];
    const int* ei_ud = (const int*)d_in[2];
    const int* ei_du = (const int*)d_in[3];
    const int* ei_uu = (const int*)d_in[4];
    const int* batch_u = (const int*)d_in[5];
    const int* batch_d = (const int*)d_in[6];
    const float* Wl1_ud = (const float*)d_in[7];  const float* bl1_ud = (const float*)d_in[8];  const float* Wr1_ud = (const float*)d_in[9];
    const float* Wl1_du = (const float*)d_in[10]; const float* bl1_du = (const float*)d_in[11]; const float* Wr1_du = (const float*)d_in[12];
    const float* Wl1_uu = (const float*)d_in[13]; const float* bl1_uu = (const float*)d_in[14]; const float* Wr1_uu = (const float*)d_in[15];
    const float* Wl2_ud = (const float*)d_in[16]; const float* bl2_ud = (const float*)d_in[17]; const float* Wr2_ud = (const float*)d_in[18];
    const float* Wl2_du = (const float*)d_in[19]; const float* bl2_du = (const float*)d_in[20]; const float* Wr2_du = (const float*)d_in[21];
    const float* Wl2_uu = (const float*)d_in[22]; const float* bl2_uu = (const float*)d_in[23]; const float* Wr2_uu = (const float*)d_in[24];
    const float* W1 = (const float*)d_in[25]; const float* b1 = (const float*)d_in[26];
    const float* W2 = (const float*)d_in[27]; const float* b2 = (const float*)d_in[28];
    (void)n_in; (void)out_size; (void)ws_size;

    const int Nu = in_sizes[0] / 128;
    const int Nd = in_sizes[1] / 128;
    const int E_ud = in_sizes[2] / 2;
    const int E_du = in_sizes[3] / 2;
    const int E_uu = in_sizes[4] / 2;

    char* ws = (char*)d_ws;
    size_t off = 0;
    auto alloc = [&](size_t bytes) -> void* {
        void* p = ws + off;
        off = (off + bytes + 255) & ~(size_t)255;
        return p;
    };
    int* csr_ud = (int*)alloc((size_t)E_ud * 4);
    int* csr_du = (int*)alloc((size_t)E_du * 4);
    int* csr_uu = (int*)alloc((size_t)E_uu * 4);
    int* rp_ud = (int*)alloc((size_t)(Nd + 1) * 4);
    int* rp_du = (int*)alloc((size_t)(Nu + 1) * 4);
    int* rp_uu = (int*)alloc((size_t)(Nu + 1) * 4);
    int* deg_ud = (int*)alloc((size_t)Nd * 4);
    int* deg_du = (int*)alloc((size_t)Nu * 4);
    int* deg_uu = (int*)alloc((size_t)Nu * 4);
    char* zero1_end = ws + off;
    ushort* rank_ud = (ushort*)alloc((size_t)E_ud * 2);
    ushort* rank_du = (ushort*)alloc((size_t)E_du * 2);
    ushort* rank_uu = (ushort*)alloc((size_t)E_uu * 2);
    ushort* xb_u = (ushort*)alloc((size_t)Nu * 128 * 2);
    ushort* xb_d = (ushort*)alloc((size_t)Nd * 128 * 2);
    ushort* mean_du = (ushort*)alloc((size_t)Nu * 128 * 2);
    ushort* mean_uu = (ushort*)alloc((size_t)Nu * 128 * 2);
    ushort* mean_ud = (ushort*)alloc((size_t)Nd * 128 * 2);
    ushort* u1b = (ushort*)alloc((size_t)Nu * 128 * 2);
    ushort* d1b = (ushort*)alloc((size_t)Nd * 128 * 2);
    float* pmdu = (float*)alloc((size_t)REP * NG * 128 * 4);
    float* pmuu = (float*)alloc((size_t)REP * NG * 128 * 4);
    float* pmud = (float*)alloc((size_t)REP * NG * 128 * 4);
    char* zero2_end = ws + off;
    float* pu1  = (float*)alloc(NG * 128 * 4);
    float* pd1  = (float*)alloc(NG * 128 * 4);
    int* bnd_u = (int*)alloc((NG + 1) * 4);
    int* bnd_d = (int*)alloc((NG + 1) * 4);
    // bf16 transposed weights [n][k]
    ushort* Wt_ru  = (ushort*)alloc(128 * 128 * 2);   // Wr1_du + Wr1_uu
    ushort* Wt_ldu = (ushort*)alloc(128 * 128 * 2);
    ushort* Wt_luu = (ushort*)alloc(128 * 128 * 2);
    ushort* Wt_rud = (ushort*)alloc(128 * 128 * 2);
    ushort* Wt_lud = (ushort*)alloc(128 * 128 * 2);
    float* b1s_u  = (float*)alloc(128 * 4);

    const int* dst_ud = ei_ud + E_ud;
    const int* dst_du = ei_du + E_du;
    const int* dst_uu = ei_uu + E_uu;

    // ---- CSR build: hist(+rank) -> scan -> atomic-free fill ----
    hipMemsetAsync(deg_ud, 0, (size_t)(zero1_end - (char*)deg_ud), stream);
    histrank_kernel<<<2048, 256, 0, stream>>>(dst_ud, E_ud, deg_ud, rank_ud);
    histrank_kernel<<<2048, 256, 0, stream>>>(dst_du, E_du, deg_du, rank_du);
    histrank_kernel<<<2048, 256, 0, stream>>>(dst_uu, E_uu, deg_uu, rank_uu);
    scan3_kernel<<<3, 1024, 0, stream>>>(deg_ud, rp_ud, Nd, deg_du, rp_du, Nu, deg_uu, rp_uu, Nu);
    fill_kernel<<<2048, 256, 0, stream>>>(ei_ud, dst_ud, rank_ud, E_ud, rp_ud, csr_ud);
    fill_kernel<<<2048, 256, 0, stream>>>(ei_du, dst_du, rank_du, E_du, rp_du, csr_du);
    fill_kernel<<<2048, 256, 0, stream>>>(ei_uu, dst_uu, rank_uu, E_uu, rp_uu, csr_uu);

    // ---- graph boundaries, bf16 inputs, weight prep ----
    bounds_kernel<<<2, NG + 1, 0, stream>>>(batch_u, Nu, batch_d, Nd, bnd_u, bnd_d);
    cvt_kernel<<<(Nu * 32 + 255) / 256, 256, 0, stream>>>(x_user, xb_u, Nu * 32);
    cvt_kernel<<<(Nd * 32 + 255) / 256, 256, 0, stream>>>(x_drug, xb_d, Nd * 32);
    wprep_kernel<<<5, 256, 0, stream>>>(Wr1_du, Wr1_uu, Wt_ru,
                                        Wl1_du, Wt_ldu, Wl1_uu, Wt_luu,
                                        Wr1_ud, Wt_rud, Wl1_ud, Wt_lud);
    add2_kernel<<<1, 128, 0, stream>>>(bl1_du, bl1_uu, b1s_u, 128);

    // ---- layer-1 aggregation ----
    agg_kernel<<<(Nu + 3) / 4, 256, 0, stream>>>(xb_d, rp_du, csr_du, Nu, mean_du);
    agg_kernel<<<(Nu + 3) / 4, 256, 0, stream>>>(xb_u, rp_uu, csr_uu, Nu, mean_uu);
    agg_kernel<<<(Nd + 3) / 4, 256, 0, stream>>>(xb_u, rp_ud, csr_ud, Nd, mean_ud);

    // ---- layer-1 MFMA GEMMs (u1: 3 terms, d1: 2 terms) -> bf16 ----
    gemm_mfma<3><<<(Nu + 63) / 64, 256, 0, stream>>>(xb_u, mean_du, mean_uu,
                                                     Wt_ru, Wt_ldu, Wt_luu, Nu, b1s_u, u1b);
    gemm_mfma<2><<<(Nd + 63) / 64, 256, 0, stream>>>(xb_d, mean_ud, nullptr,
                                                     Wt_rud, Wt_lud, nullptr, Nd, bl1_ud, d1b);

    // ---- layer 2: fused CSR-mean + per-graph pool (8 rows/wave, replicated pools) ----
    hipMemsetAsync(pmdu, 0, (size_t)(zero2_end - (char*)pmdu), stream);
    aggpool_kernel<<<(Nu + 31) / 32, 256, 0, stream>>>(d1b, rp_du, csr_du, batch_u, Nu, pmdu);
    aggpool_kernel<<<(Nu + 31) / 32, 256, 0, stream>>>(u1b, rp_uu, csr_uu, batch_u, Nu, pmuu);
    aggpool_kernel<<<(Nd + 31) / 32, 256, 0, stream>>>(u1b, rp_ud, csr_ud, batch_d, Nd, pmud);

    // ---- root-term pools (direct store) ----
    rowpool_kernel<<<NG, 256, 0, stream>>>(u1b, bnd_u, pu1);
    rowpool_kernel<<<NG, 256, 0, stream>>>(d1b, bnd_d, pd1);

    // ---- graph-level layer-2 matmuls + MLP + log_softmax ----
    final_kernel<<<NG, 128, 0, stream>>>(pmdu, pmuu, pmud, pu1, pd1, bnd_u, bnd_d,
                                         Wl2_du, bl2_du, Wr2_du,
                                         Wl2_uu, bl2_uu, Wr2_uu,
                                         Wl2_ud, bl2_ud, Wr2_ud,
                                         W1, b1, W2, b2, (float*)d_out);
}